// Round 1
// baseline (1350.459 us; speedup 1.0000x reference)
//
#include <hip/hip_runtime.h>
#include <hip/hip_bf16.h>

typedef __attribute__((ext_vector_type(8))) short short8;
typedef __attribute__((ext_vector_type(4))) float f32x4;

#define B_   2048
#define S_   67
#define M_   (B_*S_)     // 137216
#define HID_ 512
#define H_   8
#define KVH_ 4
#define D_   64

__device__ __forceinline__ unsigned f2bf_u(float f){
  union { __hip_bfloat16 h; unsigned short u; } c; c.h = __float2bfloat16(f); return (unsigned)c.u;
}
__device__ __forceinline__ float bfu2f(unsigned u){
  union { unsigned short u; __hip_bfloat16 h; } c; c.u = (unsigned short)u; return __bfloat162float(c.h);
}
__device__ __forceinline__ unsigned pack2(float a, float b){ return f2bf_u(a) | (f2bf_u(b) << 16); }

__device__ __forceinline__ void unpack8(uint4 v, float* o){
  o[0]=bfu2f(v.x & 0xffffu); o[1]=bfu2f(v.x >> 16);
  o[2]=bfu2f(v.y & 0xffffu); o[3]=bfu2f(v.y >> 16);
  o[4]=bfu2f(v.z & 0xffffu); o[5]=bfu2f(v.z >> 16);
  o[6]=bfu2f(v.w & 0xffffu); o[7]=bfu2f(v.w >> 16);
}

// ---------------- weight transpose + bf16 convert ----------------
// src: [512][ncols] fp32 (row-major [k][n]); dst row (row0+n) gets src[:, n] as bf16, K=512 inner.
__global__ __launch_bounds__(256) void transpose_w(const float* __restrict__ src, int ncols,
                                                   unsigned short* __restrict__ dst, int row0){
  __shared__ float tile[32][33];
  const int tx = threadIdx.x & 31, ty = threadIdx.x >> 5;
  const int nb = blockIdx.x * 32, kb = blockIdx.y * 32;
  #pragma unroll
  for (int i = 0; i < 4; ++i){
    int r = ty + i*8;
    tile[r][tx] = src[(size_t)(kb + r)*ncols + nb + tx];
  }
  __syncthreads();
  #pragma unroll
  for (int i = 0; i < 4; ++i){
    int r = ty + i*8; // n within tile
    dst[(size_t)(row0 + nb + r)*512 + kb + tx] = (unsigned short)f2bf_u(tile[tx][r]);
  }
}

// ---------------- bf16 MFMA GEMM: out[M][N] = in[M][512] @ Wt^T (Wt is [N][512]) ----------------
// 128x128 tile, 4 waves (2x2), each wave 64x64 via 4x4 mfma_f32_16x16x32_bf16 frags.
// LDS tiles 128x32 bf16 with 16B-block XOR swizzle (block ^= row&3) for conflict-light b128 reads.
template<bool IN_BF16, bool OUT_F32>
__global__ __launch_bounds__(256) void gemm_k(const void* __restrict__ inp,
                                              const unsigned short* __restrict__ Wt,
                                              void* __restrict__ outp, int N){
  __shared__ unsigned short As[128*32];
  __shared__ unsigned short Bs[128*32];
  const int t = threadIdx.x;
  const int m0 = blockIdx.y * 128;
  const int n0 = blockIdx.x * 128;
  const int l = t & 63;
  const int wid = t >> 6;
  const int wr = wid >> 1, wc = wid & 1;

  f32x4 acc[4][4];
  #pragma unroll
  for (int f = 0; f < 4; ++f)
    #pragma unroll
    for (int g = 0; g < 4; ++g) acc[f][g] = (f32x4){0.f, 0.f, 0.f, 0.f};

  for (int k0 = 0; k0 < 512; k0 += 32){
    __syncthreads();
    if (IN_BF16){
      const unsigned short* X = (const unsigned short*)inp;
      #pragma unroll
      for (int i = 0; i < 2; ++i){
        int f = i*256 + t; int row = f >> 2, c8 = f & 3;
        uint4 v = *reinterpret_cast<const uint4*>(X + (size_t)(m0+row)*512 + k0 + c8*8);
        *reinterpret_cast<uint4*>((char*)As + row*64 + ((c8 ^ (row & 3)) << 4)) = v;
      }
    } else {
      const float* X = (const float*)inp;
      #pragma unroll
      for (int i = 0; i < 2; ++i){
        int f = i*256 + t; int row = f >> 2, c8 = f & 3;
        const float* p = X + (size_t)(m0+row)*512 + k0 + c8*8;
        float4 va = *reinterpret_cast<const float4*>(p);
        float4 vb = *reinterpret_cast<const float4*>(p + 4);
        uint4 u = { pack2(va.x, va.y), pack2(va.z, va.w), pack2(vb.x, vb.y), pack2(vb.z, vb.w) };
        *reinterpret_cast<uint4*>((char*)As + row*64 + ((c8 ^ (row & 3)) << 4)) = u;
      }
    }
    #pragma unroll
    for (int i = 0; i < 2; ++i){
      int f = i*256 + t; int n = f >> 2, c8 = f & 3;
      uint4 v = *reinterpret_cast<const uint4*>(Wt + (size_t)(n0+n)*512 + k0 + c8*8);
      *reinterpret_cast<uint4*>((char*)Bs + n*64 + ((c8 ^ (n & 3)) << 4)) = v;
    }
    __syncthreads();

    short8 av[4], bv[4];
    const int kb = l >> 4;
    #pragma unroll
    for (int f = 0; f < 4; ++f){
      int mr = wr*64 + f*16 + (l & 15);
      av[f] = *reinterpret_cast<const short8*>((const char*)As + mr*64 + ((kb ^ (mr & 3)) << 4));
      int nr = wc*64 + f*16 + (l & 15);
      bv[f] = *reinterpret_cast<const short8*>((const char*)Bs + nr*64 + ((kb ^ (nr & 3)) << 4));
    }
    #pragma unroll
    for (int f = 0; f < 4; ++f)
      #pragma unroll
      for (int g = 0; g < 4; ++g)
        acc[f][g] = __builtin_amdgcn_mfma_f32_16x16x32_bf16(av[f], bv[g], acc[f][g], 0, 0, 0);
  }

  const int r4 = (l >> 4)*4, cc = l & 15;
  #pragma unroll
  for (int f = 0; f < 4; ++f){
    #pragma unroll
    for (int g = 0; g < 4; ++g){
      #pragma unroll
      for (int r = 0; r < 4; ++r){
        size_t row = (size_t)(m0 + wr*64 + f*16 + r4 + r);
        size_t col = (size_t)(n0 + wc*64 + g*16 + cc);
        float v = acc[f][g][r];
        if (OUT_F32) ((float*)outp)[row*(size_t)N + col] = v;
        else ((unsigned short*)outp)[row*(size_t)N + col] = (unsigned short)f2bf_u(v);
      }
    }
  }
}

// ---------------- attention: one block per (b, kvh); G=2 query heads ----------------
// qkv: [M][1024] bf16 (q cols 0..511, k 512..767, v 768..1023). RMSNorm fused at load.
// fp32 vector QK^T / softmax / PV with 4x4 register tiling; S padded to 68.
__global__ __launch_bounds__(256) void attn_k(const unsigned short* __restrict__ qkv,
                                              const float* __restrict__ qnw,
                                              const float* __restrict__ knw,
                                              unsigned short* __restrict__ attn){
  __shared__ float Ks[68*64];
  __shared__ float Qs[68*64];
  __shared__ unsigned short Vs[68*64];
  __shared__ float Ps[68*68];
  const int t = threadIdx.x;
  const int b = blockIdx.x >> 2, kvh = blockIdx.x & 3;
  const size_t rowbase = (size_t)b * 67;
  const int q = t & 3, d0 = q * 16;

  // ---- stage K (normed, fp32) and V (raw bf16) ----
  for (int sr = (t >> 2); sr < 68; sr += 64){
    if (sr < 67){
      const unsigned short* kp = qkv + (rowbase + sr)*1024 + 512 + kvh*64 + d0;
      uint4 ua = *reinterpret_cast<const uint4*>(kp);
      uint4 ub = *reinterpret_cast<const uint4*>(kp + 8);
      float kv[16]; unpack8(ua, kv); unpack8(ub, kv + 8);
      float ss = 0.f;
      #pragma unroll
      for (int j = 0; j < 16; ++j) ss += kv[j]*kv[j];
      ss += __shfl_xor(ss, 1); ss += __shfl_xor(ss, 2);
      float inv = rsqrtf(ss*(1.0f/64.0f) + 1e-5f);
      #pragma unroll
      for (int j = 0; j < 16; ++j) kv[j] *= inv * knw[d0 + j];
      #pragma unroll
      for (int jj = 0; jj < 4; ++jj){
        int bb = (d0 >> 2) + jj;
        *reinterpret_cast<float4*>(&Ks[sr*64 + ((bb ^ (sr & 15)) << 2)]) =
            make_float4(kv[jj*4], kv[jj*4+1], kv[jj*4+2], kv[jj*4+3]);
      }
      const unsigned short* vp = qkv + (rowbase + sr)*1024 + 768 + kvh*64 + d0;
      uint4 va = *reinterpret_cast<const uint4*>(vp);
      uint4 vb = *reinterpret_cast<const uint4*>(vp + 8);
      uint2 blocks[4] = { {va.x, va.y}, {va.z, va.w}, {vb.x, vb.y}, {vb.z, vb.w} };
      #pragma unroll
      for (int jj = 0; jj < 4; ++jj){
        int bb = (d0 >> 2) + jj;
        *reinterpret_cast<uint2*>(&Vs[sr*64 + ((bb ^ (sr & 15)) << 2)]) = blocks[jj];
      }
    } else {
      #pragma unroll
      for (int jj = 0; jj < 4; ++jj){
        int bb = (d0 >> 2) + jj;
        *reinterpret_cast<float4*>(&Ks[sr*64 + ((bb ^ (sr & 15)) << 2)]) = make_float4(0,0,0,0);
        *reinterpret_cast<uint2*>(&Vs[sr*64 + ((bb ^ (sr & 15)) << 2)]) = (uint2){0u, 0u};
      }
    }
  }

  for (int g = 0; g < 2; ++g){
    const int h = kvh*2 + g;
    // ---- stage Q head h (normed) ----
    for (int sr = (t >> 2); sr < 68; sr += 64){
      if (sr < 67){
        const unsigned short* qp = qkv + (rowbase + sr)*1024 + h*64 + d0;
        uint4 ua = *reinterpret_cast<const uint4*>(qp);
        uint4 ub = *reinterpret_cast<const uint4*>(qp + 8);
        float qv[16]; unpack8(ua, qv); unpack8(ub, qv + 8);
        float ss = 0.f;
        #pragma unroll
        for (int j = 0; j < 16; ++j) ss += qv[j]*qv[j];
        ss += __shfl_xor(ss, 1); ss += __shfl_xor(ss, 2);
        float inv = rsqrtf(ss*(1.0f/64.0f) + 1e-5f);
        #pragma unroll
        for (int j = 0; j < 16; ++j) qv[j] *= inv * qnw[d0 + j];
        #pragma unroll
        for (int jj = 0; jj < 4; ++jj){
          int bb = (d0 >> 2) + jj;
          *reinterpret_cast<float4*>(&Qs[sr*64 + ((bb ^ (sr & 15)) << 2)]) =
              make_float4(qv[jj*4], qv[jj*4+1], qv[jj*4+2], qv[jj*4+3]);
        }
      } else {
        #pragma unroll
        for (int jj = 0; jj < 4; ++jj){
          int bb = (d0 >> 2) + jj;
          *reinterpret_cast<float4*>(&Qs[sr*64 + ((bb ^ (sr & 15)) << 2)]) = make_float4(0,0,0,0);
        }
      }
    }
    __syncthreads();

    // ---- scores: 17x17 grid of 4x4 patches ----
    for (int pi = t; pi < 289; pi += 256){
      const int pq = pi / 17, pk = pi % 17;
      const int r0 = pq*4, c0 = pk*4;
      float acc[4][4];
      #pragma unroll
      for (int r = 0; r < 4; ++r)
        #pragma unroll
        for (int c = 0; c < 4; ++c) acc[r][c] = 0.f;
      for (int d = 0; d < 64; d += 4){
        float qvr[4][4], kvf[4][4];
        const int bb = d >> 2;
        #pragma unroll
        for (int r = 0; r < 4; ++r){
          int row = r0 + r;
          *reinterpret_cast<float4*>(qvr[r]) =
              *reinterpret_cast<const float4*>(&Qs[row*64 + ((bb ^ (row & 15)) << 2)]);
        }
        #pragma unroll
        for (int c = 0; c < 4; ++c){
          int row = c0 + c;
          *reinterpret_cast<float4*>(kvf[c]) =
              *reinterpret_cast<const float4*>(&Ks[row*64 + ((bb ^ (row & 15)) << 2)]);
        }
        #pragma unroll
        for (int r = 0; r < 4; ++r)
          #pragma unroll
          for (int c = 0; c < 4; ++c)
            #pragma unroll
            for (int j = 0; j < 4; ++j)
              acc[r][c] += qvr[r][j] * kvf[c][j];
      }
      #pragma unroll
      for (int r = 0; r < 4; ++r){
        int row = r0 + r;
        float w[4];
        #pragma unroll
        for (int c = 0; c < 4; ++c){
          int col = c0 + c;
          w[c] = (col < 67) ? acc[r][c]*0.125f : -1e30f;
        }
        int pb = (pk < 16) ? (pk ^ (row & 15)) : 16;
        *reinterpret_cast<float4*>(&Ps[row*68 + pb*4]) = make_float4(w[0], w[1], w[2], w[3]);
      }
    }
    __syncthreads();

    // ---- softmax: one row per 4-lane group ----
    for (int sq = (t >> 2); sq < 67; sq += 64){
      float mx = -1e30f;
      for (int c = q; c < 68; c += 4){
        int bb = c >> 2; int pb = (bb < 16) ? (bb ^ (sq & 15)) : 16;
        mx = fmaxf(mx, Ps[sq*68 + pb*4 + (c & 3)]);
      }
      mx = fmaxf(mx, __shfl_xor(mx, 1));
      mx = fmaxf(mx, __shfl_xor(mx, 2));
      float sm = 0.f;
      for (int c = q; c < 68; c += 4){
        int bb = c >> 2; int pb = (bb < 16) ? (bb ^ (sq & 15)) : 16;
        float e = __expf(Ps[sq*68 + pb*4 + (c & 3)] - mx);
        Ps[sq*68 + pb*4 + (c & 3)] = e;
        sm += e;
      }
      sm += __shfl_xor(sm, 1);
      sm += __shfl_xor(sm, 2);
      float inv = 1.0f / sm;
      for (int c = q; c < 68; c += 4){
        int bb = c >> 2; int pb = (bb < 16) ? (bb ^ (sq & 15)) : 16;
        Ps[sq*68 + pb*4 + (c & 3)] *= inv;
      }
    }
    __syncthreads();

    // ---- PV: 17x16 grid of 4x4 patches, write attn_out bf16 ----
    for (int pi = t; pi < 272; pi += 256){
      const int pq = pi >> 4, pd = pi & 15;
      const int r0 = pq*4, dc = pd*4;
      float acc[4][4];
      #pragma unroll
      for (int r = 0; r < 4; ++r)
        #pragma unroll
        for (int c = 0; c < 4; ++c) acc[r][c] = 0.f;
      for (int sk = 0; sk < 68; sk += 4){
        float pvr[4][4], vvf[4][4];
        const int bb = sk >> 2;
        #pragma unroll
        for (int r = 0; r < 4; ++r){
          int row = r0 + r;
          int pb = (bb < 16) ? (bb ^ (row & 15)) : 16;
          *reinterpret_cast<float4*>(pvr[r]) = *reinterpret_cast<const float4*>(&Ps[row*68 + pb*4]);
        }
        #pragma unroll
        for (int j = 0; j < 4; ++j){
          int vr = sk + j;
          ushort4 v4 = *reinterpret_cast<const ushort4*>(&Vs[vr*64 + ((pd ^ (vr & 15)) << 2)]);
          vvf[j][0] = bfu2f(v4.x); vvf[j][1] = bfu2f(v4.y);
          vvf[j][2] = bfu2f(v4.z); vvf[j][3] = bfu2f(v4.w);
        }
        #pragma unroll
        for (int r = 0; r < 4; ++r)
          #pragma unroll
          for (int c = 0; c < 4; ++c)
            #pragma unroll
            for (int j = 0; j < 4; ++j)
              acc[r][c] += pvr[r][j] * vvf[j][c];
      }
      #pragma unroll
      for (int r = 0; r < 4; ++r){
        int row = r0 + r;
        if (row < 67){
          ushort4 u;
          u.x = (unsigned short)f2bf_u(acc[r][0]);
          u.y = (unsigned short)f2bf_u(acc[r][1]);
          u.z = (unsigned short)f2bf_u(acc[r][2]);
          u.w = (unsigned short)f2bf_u(acc[r][3]);
          *reinterpret_cast<ushort4*>(&attn[(rowbase + row)*512 + h*64 + dc]) = u;
        }
      }
    }
    __syncthreads();  // protect Qs/Ps before next head overwrites
  }
}

extern "C" void kernel_launch(void* const* d_in, const int* in_sizes, int n_in,
                              void* d_out, int out_size, void* d_ws, size_t ws_size,
                              hipStream_t stream){
  const float* x   = (const float*)d_in[0];
  const float* wq  = (const float*)d_in[1];
  const float* wk  = (const float*)d_in[2];
  const float* wv  = (const float*)d_in[3];
  const float* wo  = (const float*)d_in[4];
  const float* qnw = (const float*)d_in[5];
  const float* knw = (const float*)d_in[6];

  unsigned short* Wt   = (unsigned short*)d_ws;          // [1024][512] bf16 (q|k|v cols as rows)
  unsigned short* Wot  = Wt + 1024*512;                  // [512][512] bf16
  unsigned short* qkv  = Wot + 512*512;                  // [M][1024] bf16
  unsigned short* attn = qkv + (size_t)M_*1024;          // [M][512] bf16

  // weight prep (tiny)
  transpose_w<<<dim3(16,16), 256, 0, stream>>>(wq, 512, Wt, 0);
  transpose_w<<<dim3(8,16),  256, 0, stream>>>(wk, 256, Wt, 512);
  transpose_w<<<dim3(8,16),  256, 0, stream>>>(wv, 256, Wt, 768);
  transpose_w<<<dim3(16,16), 256, 0, stream>>>(wo, 512, Wot, 0);

  // QKV projection: [M][512] fp32 @ -> [M][1024] bf16
  gemm_k<false,false><<<dim3(8, M_/128), 256, 0, stream>>>(x, Wt, qkv, 1024);

  // attention (RMSNorm fused at load)
  attn_k<<<dim3(B_*KVH_), 256, 0, stream>>>(qkv, qnw, knw, attn);

  // output projection: [M][512] bf16 @ -> [M][512] fp32
  gemm_k<true,true><<<dim3(4, M_/128), 256, 0, stream>>>(attn, Wot, d_out, 512);
}

// Round 2
// 814.576 us; speedup vs baseline: 1.6579x; 1.6579x over previous
//
#include <hip/hip_runtime.h>
#include <hip/hip_bf16.h>

typedef __attribute__((ext_vector_type(8))) short short8;
typedef __attribute__((ext_vector_type(4))) float f32x4;

#define B_   2048
#define S_   67
#define M_   (B_*S_)     // 137216
#define HID_ 512
#define H_   8
#define KVH_ 4
#define D_   64

__device__ __forceinline__ unsigned f2bf_u(float f){
  union { __hip_bfloat16 h; unsigned short u; } c; c.h = __float2bfloat16(f); return (unsigned)c.u;
}
__device__ __forceinline__ float bfu2f(unsigned u){
  union { unsigned short u; __hip_bfloat16 h; } c; c.u = (unsigned short)u; return __bfloat162float(c.h);
}
__device__ __forceinline__ unsigned pack2(float a, float b){ return f2bf_u(a) | (f2bf_u(b) << 16); }

__device__ __forceinline__ void unpack8(uint4 v, float* o){
  o[0]=bfu2f(v.x & 0xffffu); o[1]=bfu2f(v.x >> 16);
  o[2]=bfu2f(v.y & 0xffffu); o[3]=bfu2f(v.y >> 16);
  o[4]=bfu2f(v.z & 0xffffu); o[5]=bfu2f(v.z >> 16);
  o[6]=bfu2f(v.w & 0xffffu); o[7]=bfu2f(v.w >> 16);
}

union S8 { short8 v; unsigned short u[8]; };

// ---------------- weight transpose + bf16 convert ----------------
__global__ __launch_bounds__(256) void transpose_w(const float* __restrict__ src, int ncols,
                                                   unsigned short* __restrict__ dst, int row0){
  __shared__ float tile[32][33];
  const int tx = threadIdx.x & 31, ty = threadIdx.x >> 5;
  const int nb = blockIdx.x * 32, kb = blockIdx.y * 32;
  #pragma unroll
  for (int i = 0; i < 4; ++i){
    int r = ty + i*8;
    tile[r][tx] = src[(size_t)(kb + r)*ncols + nb + tx];
  }
  __syncthreads();
  #pragma unroll
  for (int i = 0; i < 4; ++i){
    int r = ty + i*8; // n within tile
    dst[(size_t)(row0 + nb + r)*512 + kb + tx] = (unsigned short)f2bf_u(tile[tx][r]);
  }
}

// ---------------- bf16 MFMA GEMM: out[M][N] = in[M][512] @ Wt^T (Wt is [N][512]) ----------------
template<bool IN_BF16, bool OUT_F32>
__global__ __launch_bounds__(256) void gemm_k(const void* __restrict__ inp,
                                              const unsigned short* __restrict__ Wt,
                                              void* __restrict__ outp, int N){
  __shared__ unsigned short As[128*32];
  __shared__ unsigned short Bs[128*32];
  const int t = threadIdx.x;
  const int m0 = blockIdx.y * 128;
  const int n0 = blockIdx.x * 128;
  const int l = t & 63;
  const int wid = t >> 6;
  const int wr = wid >> 1, wc = wid & 1;

  f32x4 acc[4][4];
  #pragma unroll
  for (int f = 0; f < 4; ++f)
    #pragma unroll
    for (int g = 0; g < 4; ++g) acc[f][g] = (f32x4){0.f, 0.f, 0.f, 0.f};

  for (int k0 = 0; k0 < 512; k0 += 32){
    __syncthreads();
    if (IN_BF16){
      const unsigned short* X = (const unsigned short*)inp;
      #pragma unroll
      for (int i = 0; i < 2; ++i){
        int f = i*256 + t; int row = f >> 2, c8 = f & 3;
        uint4 v = *reinterpret_cast<const uint4*>(X + (size_t)(m0+row)*512 + k0 + c8*8);
        *reinterpret_cast<uint4*>((char*)As + row*64 + ((c8 ^ (row & 3)) << 4)) = v;
      }
    } else {
      const float* X = (const float*)inp;
      #pragma unroll
      for (int i = 0; i < 2; ++i){
        int f = i*256 + t; int row = f >> 2, c8 = f & 3;
        const float* p = X + (size_t)(m0+row)*512 + k0 + c8*8;
        float4 va = *reinterpret_cast<const float4*>(p);
        float4 vb = *reinterpret_cast<const float4*>(p + 4);
        uint4 u = { pack2(va.x, va.y), pack2(va.z, va.w), pack2(vb.x, vb.y), pack2(vb.z, vb.w) };
        *reinterpret_cast<uint4*>((char*)As + row*64 + ((c8 ^ (row & 3)) << 4)) = u;
      }
    }
    #pragma unroll
    for (int i = 0; i < 2; ++i){
      int f = i*256 + t; int n = f >> 2, c8 = f & 3;
      uint4 v = *reinterpret_cast<const uint4*>(Wt + (size_t)(n0+n)*512 + k0 + c8*8);
      *reinterpret_cast<uint4*>((char*)Bs + n*64 + ((c8 ^ (n & 3)) << 4)) = v;
    }
    __syncthreads();

    short8 av[4], bv[4];
    const int kb = l >> 4;
    #pragma unroll
    for (int f = 0; f < 4; ++f){
      int mr = wr*64 + f*16 + (l & 15);
      av[f] = *reinterpret_cast<const short8*>((const char*)As + mr*64 + ((kb ^ (mr & 3)) << 4));
      int nr = wc*64 + f*16 + (l & 15);
      bv[f] = *reinterpret_cast<const short8*>((const char*)Bs + nr*64 + ((kb ^ (nr & 3)) << 4));
    }
    #pragma unroll
    for (int f = 0; f < 4; ++f)
      #pragma unroll
      for (int g = 0; g < 4; ++g)
        acc[f][g] = __builtin_amdgcn_mfma_f32_16x16x32_bf16(av[f], bv[g], acc[f][g], 0, 0, 0);
  }

  const int r4 = (l >> 4)*4, cc = l & 15;
  #pragma unroll
  for (int f = 0; f < 4; ++f){
    #pragma unroll
    for (int g = 0; g < 4; ++g){
      #pragma unroll
      for (int r = 0; r < 4; ++r){
        size_t row = (size_t)(m0 + wr*64 + f*16 + r4 + r);
        size_t col = (size_t)(n0 + wc*64 + g*16 + cc);
        float v = acc[f][g][r];
        if (OUT_F32) ((float*)outp)[row*(size_t)N + col] = v;
        else ((unsigned short*)outp)[row*(size_t)N + col] = (unsigned short)f2bf_u(v);
      }
    }
  }
}

// ---------------- MFMA attention: one block per (b, kvh), 5 waves ----------------
// 10 m-strips (2 heads x 5 strips of 16 q-rows) -> 2 strips/wave.
// Q,K fragments straight from global into MFMA layout, RMSNorm in registers
// (norm weights folded into K). Softmax fully in registers. P goes through a
// wave-private swizzled LDS buffer to re-shape into A-fragments; V transposed
// into swizzled LDS once (B-operand of PV needs V^T).
__global__ __launch_bounds__(320) void attn_k(const unsigned short* __restrict__ qkv,
                                              const float* __restrict__ qnw,
                                              const float* __restrict__ knw,
                                              unsigned short* __restrict__ attn){
  __shared__ unsigned short Vt[64*128];       // V^T [d][s], s padded to 128, swizzled
  __shared__ unsigned short Pb[5][16*128];    // per-wave P [16 rows][s pad 128], swizzled
  const int t = threadIdx.x;
  const int b = blockIdx.x >> 2, kvh = blockIdx.x & 3;
  const size_t rowbase = (size_t)b * 67;
  const int l = t & 63, w = t >> 6;
  const int lr = l & 15, lk = l >> 4;

  // ---- stage V transposed (zeros for s>=67) ----
  {
    const int dq = (t & 3) << 4;
    for (int sr = (t >> 2); sr < 96; sr += 80){
      unsigned short vs[16];
      if (sr < 67){
        const unsigned short* vp = qkv + (rowbase + sr)*1024 + 768 + kvh*64 + dq;
        uint4 va = *reinterpret_cast<const uint4*>(vp);
        uint4 vb = *reinterpret_cast<const uint4*>(vp + 8);
        vs[0]=va.x&0xffffu; vs[1]=va.x>>16; vs[2]=va.y&0xffffu; vs[3]=va.y>>16;
        vs[4]=va.z&0xffffu; vs[5]=va.z>>16; vs[6]=va.w&0xffffu; vs[7]=va.w>>16;
        vs[8]=vb.x&0xffffu; vs[9]=vb.x>>16; vs[10]=vb.y&0xffffu; vs[11]=vb.y>>16;
        vs[12]=vb.z&0xffffu; vs[13]=vb.z>>16; vs[14]=vb.w&0xffffu; vs[15]=vb.w>>16;
      } else {
        #pragma unroll
        for (int j = 0; j < 16; ++j) vs[j] = 0;
      }
      #pragma unroll
      for (int j = 0; j < 16; ++j){
        int d = dq + j;
        Vt[(d<<7) + ((((sr>>3) ^ ((d&7)<<1))) << 3) + (sr&7)] = vs[j];
      }
    }
  }

  // ---- per-lane norm-weight products (folded into K) ----
  float wp[16];
  #pragma unroll
  for (int ks = 0; ks < 2; ++ks)
    #pragma unroll
    for (int j = 0; j < 8; ++j){
      int idx = ks*32 + lk*8 + j;
      wp[ks*8+j] = qnw[idx] * knw[idx];
    }

  // ---- K fragments, normed+weighted, kept in registers (shared across strips) ----
  short8 kf[5][2];
  #pragma unroll
  for (int nt = 0; nt < 5; ++nt){
    int s = nt*16 + lr; if (s > 66) s = 66;
    const unsigned short* kp = qkv + (rowbase + s)*1024 + 512 + kvh*64 + lk*8;
    uint4 u0 = *reinterpret_cast<const uint4*>(kp);
    uint4 u1 = *reinterpret_cast<const uint4*>(kp + 32);
    float f[16]; unpack8(u0, f); unpack8(u1, f + 8);
    float ss = 0.f;
    #pragma unroll
    for (int j = 0; j < 16; ++j) ss += f[j]*f[j];
    ss += __shfl_xor(ss, 16); ss += __shfl_xor(ss, 32);
    float inv = rsqrtf(ss*(1.0f/64.0f) + 1e-5f);
    S8 a0, a1;
    #pragma unroll
    for (int j = 0; j < 8; ++j){
      a0.u[j] = (unsigned short)f2bf_u(f[j]   * inv * wp[j]);
      a1.u[j] = (unsigned short)f2bf_u(f[8+j] * inv * wp[8+j]);
    }
    kf[nt][0] = a0.v; kf[nt][1] = a1.v;
  }

  // ---- zero my wave's Pb (pads s=80..127 stay zero) ----
  {
    uint4 z = {0u,0u,0u,0u};
    uint4* pz = reinterpret_cast<uint4*>(Pb[w]);
    for (int i = l; i < 256; i += 64) pz[i] = z;
  }
  __syncthreads();

  #pragma unroll
  for (int pass = 0; pass < 2; ++pass){
    const int st = w + pass*5;           // 0..9
    const int g = st / 5, m0 = (st % 5) * 16;
    const int h = kvh*2 + g;

    // ---- Q fragments, normed (no weight; folded into K) ----
    short8 qf0, qf1;
    {
      int qr = m0 + lr; if (qr > 66) qr = 66;
      const unsigned short* qp = qkv + (rowbase + qr)*1024 + h*64 + lk*8;
      uint4 u0 = *reinterpret_cast<const uint4*>(qp);
      uint4 u1 = *reinterpret_cast<const uint4*>(qp + 32);
      float f[16]; unpack8(u0, f); unpack8(u1, f + 8);
      float ss = 0.f;
      #pragma unroll
      for (int j = 0; j < 16; ++j) ss += f[j]*f[j];
      ss += __shfl_xor(ss, 16); ss += __shfl_xor(ss, 32);
      float inv = rsqrtf(ss*(1.0f/64.0f) + 1e-5f);
      S8 a0, a1;
      #pragma unroll
      for (int j = 0; j < 8; ++j){
        a0.u[j] = (unsigned short)f2bf_u(f[j]   * inv);
        a1.u[j] = (unsigned short)f2bf_u(f[8+j] * inv);
      }
      qf0 = a0.v; qf1 = a1.v;
    }

    // ---- QK^T: 5 n-tiles x 2 ksteps ----
    f32x4 sa[5];
    #pragma unroll
    for (int nt = 0; nt < 5; ++nt){
      sa[nt] = (f32x4){0.f,0.f,0.f,0.f};
      sa[nt] = __builtin_amdgcn_mfma_f32_16x16x32_bf16(qf0, kf[nt][0], sa[nt], 0,0,0);
      sa[nt] = __builtin_amdgcn_mfma_f32_16x16x32_bf16(qf1, kf[nt][1], sa[nt], 0,0,0);
    }

    // ---- in-register softmax; lane holds S[lk*4+r][nt*16+lr] ----
    #pragma unroll
    for (int r = 0; r < 4; ++r){
      float mx = -1e30f;
      #pragma unroll
      for (int nt = 0; nt < 5; ++nt){
        float v = sa[nt][r]*0.125f;
        if (nt*16 + lr >= 67) v = -1e30f;
        sa[nt][r] = v; mx = fmaxf(mx, v);
      }
      mx = fmaxf(mx, __shfl_xor(mx, 1));
      mx = fmaxf(mx, __shfl_xor(mx, 2));
      mx = fmaxf(mx, __shfl_xor(mx, 4));
      mx = fmaxf(mx, __shfl_xor(mx, 8));
      float sm = 0.f;
      #pragma unroll
      for (int nt = 0; nt < 5; ++nt){
        float e = __expf(sa[nt][r] - mx);
        sa[nt][r] = e; sm += e;
      }
      sm += __shfl_xor(sm, 1);
      sm += __shfl_xor(sm, 2);
      sm += __shfl_xor(sm, 4);
      sm += __shfl_xor(sm, 8);
      float inv = 1.0f / sm;
      #pragma unroll
      for (int nt = 0; nt < 5; ++nt) sa[nt][r] *= inv;
    }

    // ---- P -> wave-private swizzled LDS (bf16) ----
    unsigned short* pb = Pb[w];
    #pragma unroll
    for (int nt = 0; nt < 5; ++nt)
      #pragma unroll
      for (int r = 0; r < 4; ++r){
        int row = lk*4 + r, col = nt*16 + lr;
        pb[(row<<7) + ((((col>>3) ^ ((row&7)<<1))) << 3) + (col&7)] =
            (unsigned short)f2bf_u(sa[nt][r]);
      }

    // ---- PV: A = P (rows=q), B = Vt (rows=d), K = s in 3 ksteps of 32 ----
    f32x4 oa[4];
    #pragma unroll
    for (int dt = 0; dt < 4; ++dt) oa[dt] = (f32x4){0.f,0.f,0.f,0.f};
    #pragma unroll
    for (int ks = 0; ks < 3; ++ks){
      int blkp = (lk + ks*4) ^ ((lr & 7) << 1);
      short8 pf = *reinterpret_cast<const short8*>(&pb[(lr<<7) + (blkp<<3)]);
      #pragma unroll
      for (int dt = 0; dt < 4; ++dt){
        int d = dt*16 + lr;
        int blkv = (lk + ks*4) ^ ((d & 7) << 1);
        short8 vf = *reinterpret_cast<const short8*>(&Vt[(d<<7) + (blkv<<3)]);
        oa[dt] = __builtin_amdgcn_mfma_f32_16x16x32_bf16(pf, vf, oa[dt], 0,0,0);
      }
    }

    // ---- write O rows (16 lanes -> 32B contiguous per (dt,r)) ----
    #pragma unroll
    for (int dt = 0; dt < 4; ++dt)
      #pragma unroll
      for (int r = 0; r < 4; ++r){
        int row = m0 + lk*4 + r;
        if (row < 67)
          attn[(rowbase + row)*512 + h*64 + dt*16 + lr] = (unsigned short)f2bf_u(oa[dt][r]);
      }
  }
}

extern "C" void kernel_launch(void* const* d_in, const int* in_sizes, int n_in,
                              void* d_out, int out_size, void* d_ws, size_t ws_size,
                              hipStream_t stream){
  const float* x   = (const float*)d_in[0];
  const float* wq  = (const float*)d_in[1];
  const float* wk  = (const float*)d_in[2];
  const float* wv  = (const float*)d_in[3];
  const float* wo  = (const float*)d_in[4];
  const float* qnw = (const float*)d_in[5];
  const float* knw = (const float*)d_in[6];

  unsigned short* Wt   = (unsigned short*)d_ws;          // [1024][512] bf16 (q|k|v cols as rows)
  unsigned short* Wot  = Wt + 1024*512;                  // [512][512] bf16
  unsigned short* qkv  = Wot + 512*512;                  // [M][1024] bf16
  unsigned short* attn = qkv + (size_t)M_*1024;          // [M][512] bf16

  // weight prep (tiny)
  transpose_w<<<dim3(16,16), 256, 0, stream>>>(wq, 512, Wt, 0);
  transpose_w<<<dim3(8,16),  256, 0, stream>>>(wk, 256, Wt, 512);
  transpose_w<<<dim3(8,16),  256, 0, stream>>>(wv, 256, Wt, 768);
  transpose_w<<<dim3(16,16), 256, 0, stream>>>(wo, 512, Wot, 0);

  // QKV projection: [M][512] fp32 @ -> [M][1024] bf16
  gemm_k<false,false><<<dim3(8, M_/128), 256, 0, stream>>>(x, Wt, qkv, 1024);

  // attention (MFMA, RMSNorm fused in registers)
  attn_k<<<dim3(B_*KVH_), 320, 0, stream>>>(qkv, qnw, knw, attn);

  // output projection: [M][512] bf16 @ -> [M][512] fp32
  gemm_k<true,true><<<dim3(4, M_/128), 256, 0, stream>>>(attn, Wot, d_out, 512);
}

// Round 3
// 794.546 us; speedup vs baseline: 1.6997x; 1.0252x over previous
//
#include <hip/hip_runtime.h>
#include <hip/hip_bf16.h>

typedef __attribute__((ext_vector_type(8))) short short8;
typedef __attribute__((ext_vector_type(4))) float f32x4;

#define B_   2048
#define S_   67
#define M_   (B_*S_)     // 137216
#define HID_ 512
#define H_   8
#define KVH_ 4
#define D_   64

__device__ __forceinline__ unsigned f2bf_u(float f){
  union { __hip_bfloat16 h; unsigned short u; } c; c.h = __float2bfloat16(f); return (unsigned)c.u;
}
__device__ __forceinline__ float bfu2f(unsigned u){
  union { unsigned short u; __hip_bfloat16 h; } c; c.u = (unsigned short)u; return __bfloat162float(c.h);
}
__device__ __forceinline__ unsigned pack2(float a, float b){ return f2bf_u(a) | (f2bf_u(b) << 16); }

__device__ __forceinline__ void unpack8(uint4 v, float* o){
  o[0]=bfu2f(v.x & 0xffffu); o[1]=bfu2f(v.x >> 16);
  o[2]=bfu2f(v.y & 0xffffu); o[3]=bfu2f(v.y >> 16);
  o[4]=bfu2f(v.z & 0xffffu); o[5]=bfu2f(v.z >> 16);
  o[6]=bfu2f(v.w & 0xffffu); o[7]=bfu2f(v.w >> 16);
}

union S8 { short8 v; unsigned short u[8]; };

// ---------------- x fp32 -> bf16 convert ----------------
__global__ __launch_bounds__(256) void cvt_bf16(const float* __restrict__ src,
                                                unsigned short* __restrict__ dst){
  long i = (long)blockIdx.x*256 + threadIdx.x;   // one uint4 (8 bf16) per thread
  const float4 a = reinterpret_cast<const float4*>(src)[2*i];
  const float4 b = reinterpret_cast<const float4*>(src)[2*i+1];
  uint4 u = { pack2(a.x,a.y), pack2(a.z,a.w), pack2(b.x,b.y), pack2(b.z,b.w) };
  reinterpret_cast<uint4*>(dst)[i] = u;
}

// ---------------- weight transpose + bf16 convert ----------------
__global__ __launch_bounds__(256) void transpose_w(const float* __restrict__ src, int ncols,
                                                   unsigned short* __restrict__ dst, int row0){
  __shared__ float tile[32][33];
  const int tx = threadIdx.x & 31, ty = threadIdx.x >> 5;
  const int nb = blockIdx.x * 32, kb = blockIdx.y * 32;
  #pragma unroll
  for (int i = 0; i < 4; ++i){
    int r = ty + i*8;
    tile[r][tx] = src[(size_t)(kb + r)*ncols + nb + tx];
  }
  __syncthreads();
  #pragma unroll
  for (int i = 0; i < 4; ++i){
    int r = ty + i*8; // n within tile
    dst[(size_t)(row0 + nb + r)*512 + kb + tx] = (unsigned short)f2bf_u(tile[tx][r]);
  }
}

// ---------------- bf16 MFMA GEMM, m97 structure ----------------
// out[M][Nld] = A[M][512] @ Bw^T  (Bw is [Nld][512] bf16, k-contiguous)
// 128x128 tile, BK=64, global_load_lds width=16 with pre-swizzled global source
// (LDS dest linear), XOR-swizzled ds_read_b128, bijective XCD block swizzle.
template<bool OUT_F32>
__global__ __launch_bounds__(256) void gemm2_k(const unsigned short* __restrict__ A,
                                               const unsigned short* __restrict__ Bw,
                                               void* __restrict__ outp, int nbx){
  __shared__ unsigned short Sh[128*64*2];
  unsigned short* As = Sh;
  unsigned short* Bs = Sh + 128*64;

  const int Nld = nbx << 7;
  // bijective XCD swizzle (gridDim.x divisible by 8): XCD x gets a contiguous wg chunk
  const int per = gridDim.x >> 3;
  const int wg  = (blockIdx.x & 7) * per + (blockIdx.x >> 3);
  const int m0 = (wg / nbx) * 128;
  const int n0 = (wg % nbx) * 128;

  const int t = threadIdx.x;
  const int l = t & 63;
  const int w = t >> 6;
  const int wr = w >> 1, wc = w & 1;
  const int lr = l & 15, lk = l >> 4;

  // staging source pre-swizzle: lane i covers LDS slot [row8 = i>>3][kblk_phys = i&7];
  // logical k-block at that slot = (i&7) ^ (i>>3)  (involution XOR by row&7)
  const int srow  = w*32 + (l >> 3);        // + j*8
  const int skblk = (l & 7) ^ (l >> 3);

  f32x4 acc[4][4];
  #pragma unroll
  for (int f = 0; f < 4; ++f)
    #pragma unroll
    for (int g = 0; g < 4; ++g) acc[f][g] = (f32x4){0.f, 0.f, 0.f, 0.f};

  for (int k0 = 0; k0 < 512; k0 += 64){
    __syncthreads();
    #pragma unroll
    for (int j = 0; j < 4; ++j){
      __builtin_amdgcn_global_load_lds(
        (const unsigned int*)(A + (size_t)(m0 + srow + j*8)*512 + k0 + skblk*8),
        (unsigned int*)(As + (w*32 + j*8)*64), 16, 0, 0);
      __builtin_amdgcn_global_load_lds(
        (const unsigned int*)(Bw + (size_t)(n0 + srow + j*8)*512 + k0 + skblk*8),
        (unsigned int*)(Bs + (w*32 + j*8)*64), 16, 0, 0);
    }
    __syncthreads();   // compiler drains vmcnt(0) before s_barrier

    #pragma unroll
    for (int ks = 0; ks < 2; ++ks){
      const int pk = ((ks*4 + lk) ^ (l & 7)) * 8;   // row&7 == l&7 for all frags
      short8 av[4], bv[4];
      #pragma unroll
      for (int f = 0; f < 4; ++f){
        av[f] = *reinterpret_cast<const short8*>(As + (wr*64 + f*16 + lr)*64 + pk);
        bv[f] = *reinterpret_cast<const short8*>(Bs + (wc*64 + f*16 + lr)*64 + pk);
      }
      #pragma unroll
      for (int f = 0; f < 4; ++f)
        #pragma unroll
        for (int g = 0; g < 4; ++g)
          acc[f][g] = __builtin_amdgcn_mfma_f32_16x16x32_bf16(av[f], bv[g], acc[f][g], 0, 0, 0);
    }
  }

  if (OUT_F32){
    float* out = (float*)outp;
    #pragma unroll
    for (int f = 0; f < 4; ++f)
      #pragma unroll
      for (int g = 0; g < 4; ++g)
        #pragma unroll
        for (int r = 0; r < 4; ++r){
          size_t row = (size_t)(m0 + wr*64 + f*16 + lk*4 + r);
          out[row*Nld + n0 + wc*64 + g*16 + lr] = acc[f][g][r];
        }
  } else {
    // C -> LDS (reuse As/Bs: 128x128 bf16 = 32 KB) -> fully coalesced uint4 stores
    __syncthreads();
    #pragma unroll
    for (int f = 0; f < 4; ++f)
      #pragma unroll
      for (int g = 0; g < 4; ++g)
        #pragma unroll
        for (int r = 0; r < 4; ++r){
          int row = wr*64 + f*16 + lk*4 + r;
          int col = wc*64 + g*16 + lr;
          Sh[row*128 + col] = (unsigned short)f2bf_u(acc[f][g][r]);
        }
    __syncthreads();
    unsigned short* out = (unsigned short*)outp;
    const uint4* Cv = reinterpret_cast<const uint4*>(Sh);
    #pragma unroll
    for (int p = 0; p < 8; ++p){
      int idx = p*256 + t;              // 2048 uint4 = 128 rows x 256B
      int row = idx >> 4, c8 = idx & 15;
      *reinterpret_cast<uint4*>(out + (size_t)(m0 + row)*Nld + n0 + c8*8) = Cv[idx];
    }
  }
}

// ---------------- MFMA attention: one block per (b, kvh), 5 waves ----------------
__global__ __launch_bounds__(320) void attn_k(const unsigned short* __restrict__ qkv,
                                              const float* __restrict__ qnw,
                                              const float* __restrict__ knw,
                                              unsigned short* __restrict__ attn){
  __shared__ unsigned short Vt[64*128];       // V^T [d][s], s padded to 128, swizzled
  __shared__ unsigned short Pb[5][16*128];    // per-wave P [16 rows][s pad 128], swizzled
  const int t = threadIdx.x;
  const int b = blockIdx.x >> 2, kvh = blockIdx.x & 3;
  const size_t rowbase = (size_t)b * 67;
  const int l = t & 63, w = t >> 6;
  const int lr = l & 15, lk = l >> 4;

  // ---- stage V transposed (zeros for s>=67) ----
  {
    const int dq = (t & 3) << 4;
    for (int sr = (t >> 2); sr < 96; sr += 80){
      unsigned short vs[16];
      if (sr < 67){
        const unsigned short* vp = qkv + (rowbase + sr)*1024 + 768 + kvh*64 + dq;
        uint4 va = *reinterpret_cast<const uint4*>(vp);
        uint4 vb = *reinterpret_cast<const uint4*>(vp + 8);
        vs[0]=va.x&0xffffu; vs[1]=va.x>>16; vs[2]=va.y&0xffffu; vs[3]=va.y>>16;
        vs[4]=va.z&0xffffu; vs[5]=va.z>>16; vs[6]=va.w&0xffffu; vs[7]=va.w>>16;
        vs[8]=vb.x&0xffffu; vs[9]=vb.x>>16; vs[10]=vb.y&0xffffu; vs[11]=vb.y>>16;
        vs[12]=vb.z&0xffffu; vs[13]=vb.z>>16; vs[14]=vb.w&0xffffu; vs[15]=vb.w>>16;
      } else {
        #pragma unroll
        for (int j = 0; j < 16; ++j) vs[j] = 0;
      }
      #pragma unroll
      for (int j = 0; j < 16; ++j){
        int d = dq + j;
        Vt[(d<<7) + ((((sr>>3) ^ ((d&7)<<1))) << 3) + (sr&7)] = vs[j];
      }
    }
  }

  // ---- per-lane norm-weight products (folded into K) ----
  float wp[16];
  #pragma unroll
  for (int ks = 0; ks < 2; ++ks)
    #pragma unroll
    for (int j = 0; j < 8; ++j){
      int idx = ks*32 + lk*8 + j;
      wp[ks*8+j] = qnw[idx] * knw[idx];
    }

  // ---- K fragments, normed+weighted, kept in registers ----
  short8 kf[5][2];
  #pragma unroll
  for (int nt = 0; nt < 5; ++nt){
    int s = nt*16 + lr; if (s > 66) s = 66;
    const unsigned short* kp = qkv + (rowbase + s)*1024 + 512 + kvh*64 + lk*8;
    uint4 u0 = *reinterpret_cast<const uint4*>(kp);
    uint4 u1 = *reinterpret_cast<const uint4*>(kp + 32);
    float f[16]; unpack8(u0, f); unpack8(u1, f + 8);
    float ss = 0.f;
    #pragma unroll
    for (int j = 0; j < 16; ++j) ss += f[j]*f[j];
    ss += __shfl_xor(ss, 16); ss += __shfl_xor(ss, 32);
    float inv = rsqrtf(ss*(1.0f/64.0f) + 1e-5f);
    S8 a0, a1;
    #pragma unroll
    for (int j = 0; j < 8; ++j){
      a0.u[j] = (unsigned short)f2bf_u(f[j]   * inv * wp[j]);
      a1.u[j] = (unsigned short)f2bf_u(f[8+j] * inv * wp[8+j]);
    }
    kf[nt][0] = a0.v; kf[nt][1] = a1.v;
  }

  // ---- zero my wave's Pb ----
  {
    uint4 z = {0u,0u,0u,0u};
    uint4* pz = reinterpret_cast<uint4*>(Pb[w]);
    for (int i = l; i < 256; i += 64) pz[i] = z;
  }
  __syncthreads();

  #pragma unroll
  for (int pass = 0; pass < 2; ++pass){
    const int st = w + pass*5;           // 0..9
    const int g = st / 5, m0 = (st % 5) * 16;
    const int h = kvh*2 + g;

    // ---- Q fragments, normed ----
    short8 qf0, qf1;
    {
      int qr = m0 + lr; if (qr > 66) qr = 66;
      const unsigned short* qp = qkv + (rowbase + qr)*1024 + h*64 + lk*8;
      uint4 u0 = *reinterpret_cast<const uint4*>(qp);
      uint4 u1 = *reinterpret_cast<const uint4*>(qp + 32);
      float f[16]; unpack8(u0, f); unpack8(u1, f + 8);
      float ss = 0.f;
      #pragma unroll
      for (int j = 0; j < 16; ++j) ss += f[j]*f[j];
      ss += __shfl_xor(ss, 16); ss += __shfl_xor(ss, 32);
      float inv = rsqrtf(ss*(1.0f/64.0f) + 1e-5f);
      S8 a0, a1;
      #pragma unroll
      for (int j = 0; j < 8; ++j){
        a0.u[j] = (unsigned short)f2bf_u(f[j]   * inv);
        a1.u[j] = (unsigned short)f2bf_u(f[8+j] * inv);
      }
      qf0 = a0.v; qf1 = a1.v;
    }

    // ---- QK^T ----
    f32x4 sa[5];
    #pragma unroll
    for (int nt = 0; nt < 5; ++nt){
      sa[nt] = (f32x4){0.f,0.f,0.f,0.f};
      sa[nt] = __builtin_amdgcn_mfma_f32_16x16x32_bf16(qf0, kf[nt][0], sa[nt], 0,0,0);
      sa[nt] = __builtin_amdgcn_mfma_f32_16x16x32_bf16(qf1, kf[nt][1], sa[nt], 0,0,0);
    }

    // ---- in-register softmax ----
    #pragma unroll
    for (int r = 0; r < 4; ++r){
      float mx = -1e30f;
      #pragma unroll
      for (int nt = 0; nt < 5; ++nt){
        float v = sa[nt][r]*0.125f;
        if (nt*16 + lr >= 67) v = -1e30f;
        sa[nt][r] = v; mx = fmaxf(mx, v);
      }
      mx = fmaxf(mx, __shfl_xor(mx, 1));
      mx = fmaxf(mx, __shfl_xor(mx, 2));
      mx = fmaxf(mx, __shfl_xor(mx, 4));
      mx = fmaxf(mx, __shfl_xor(mx, 8));
      float sm = 0.f;
      #pragma unroll
      for (int nt = 0; nt < 5; ++nt){
        float e = __expf(sa[nt][r] - mx);
        sa[nt][r] = e; sm += e;
      }
      sm += __shfl_xor(sm, 1);
      sm += __shfl_xor(sm, 2);
      sm += __shfl_xor(sm, 4);
      sm += __shfl_xor(sm, 8);
      float inv = 1.0f / sm;
      #pragma unroll
      for (int nt = 0; nt < 5; ++nt) sa[nt][r] *= inv;
    }

    // ---- P -> wave-private swizzled LDS (bf16) ----
    unsigned short* pb = Pb[w];
    #pragma unroll
    for (int nt = 0; nt < 5; ++nt)
      #pragma unroll
      for (int r = 0; r < 4; ++r){
        int row = lk*4 + r, col = nt*16 + lr;
        pb[(row<<7) + ((((col>>3) ^ ((row&7)<<1))) << 3) + (col&7)] =
            (unsigned short)f2bf_u(sa[nt][r]);
      }

    // ---- PV ----
    f32x4 oa[4];
    #pragma unroll
    for (int dt = 0; dt < 4; ++dt) oa[dt] = (f32x4){0.f,0.f,0.f,0.f};
    #pragma unroll
    for (int ks = 0; ks < 3; ++ks){
      int blkp = (lk + ks*4) ^ ((lr & 7) << 1);
      short8 pf = *reinterpret_cast<const short8*>(&pb[(lr<<7) + (blkp<<3)]);
      #pragma unroll
      for (int dt = 0; dt < 4; ++dt){
        int d = dt*16 + lr;
        int blkv = (lk + ks*4) ^ ((d & 7) << 1);
        short8 vf = *reinterpret_cast<const short8*>(&Vt[(d<<7) + (blkv<<3)]);
        oa[dt] = __builtin_amdgcn_mfma_f32_16x16x32_bf16(pf, vf, oa[dt], 0,0,0);
      }
    }

    // ---- write O ----
    #pragma unroll
    for (int dt = 0; dt < 4; ++dt)
      #pragma unroll
      for (int r = 0; r < 4; ++r){
        int row = m0 + lk*4 + r;
        if (row < 67)
          attn[(rowbase + row)*512 + h*64 + dt*16 + lr] = (unsigned short)f2bf_u(oa[dt][r]);
      }
  }
}

extern "C" void kernel_launch(void* const* d_in, const int* in_sizes, int n_in,
                              void* d_out, int out_size, void* d_ws, size_t ws_size,
                              hipStream_t stream){
  const float* x   = (const float*)d_in[0];
  const float* wq  = (const float*)d_in[1];
  const float* wk  = (const float*)d_in[2];
  const float* wv  = (const float*)d_in[3];
  const float* wo  = (const float*)d_in[4];
  const float* qnw = (const float*)d_in[5];
  const float* knw = (const float*)d_in[6];

  unsigned short* Wt   = (unsigned short*)d_ws;          // [1024][512] bf16
  unsigned short* Wot  = Wt + 1024*512;                  // [512][512] bf16
  unsigned short* qkv  = Wot + 512*512;                  // [M][1024] bf16
  unsigned short* attn = qkv + (size_t)M_*1024;          // [M][512] bf16
  unsigned short* xb   = attn;                           // alias: xb dead before attn written

  // weight prep (tiny)
  transpose_w<<<dim3(16,16), 256, 0, stream>>>(wq, 512, Wt, 0);
  transpose_w<<<dim3(8,16),  256, 0, stream>>>(wk, 256, Wt, 512);
  transpose_w<<<dim3(8,16),  256, 0, stream>>>(wv, 256, Wt, 768);
  transpose_w<<<dim3(16,16), 256, 0, stream>>>(wo, 512, Wot, 0);

  // x -> bf16 (M*512/8 uint4s)
  cvt_bf16<<<(M_*512/8 + 255)/256, 256, 0, stream>>>(x, xb);

  // QKV projection: [M][512] bf16 @ -> [M][1024] bf16
  gemm2_k<false><<<dim3(8 * (M_/128)), 256, 0, stream>>>(xb, Wt, qkv, 8);

  // attention (MFMA, RMSNorm fused in registers)
  attn_k<<<dim3(B_*KVH_), 320, 0, stream>>>(qkv, qnw, knw, attn);

  // output projection: [M][512] bf16 @ -> [M][512] fp32
  gemm2_k<true><<<dim3(4 * (M_/128)), 256, 0, stream>>>(attn, Wot, d_out, 4);
}

// Round 4
// 704.953 us; speedup vs baseline: 1.9157x; 1.1271x over previous
//
#include <hip/hip_runtime.h>
#include <hip/hip_bf16.h>

typedef __attribute__((ext_vector_type(8))) short short8;
typedef __attribute__((ext_vector_type(4))) float f32x4;

#define B_   2048
#define S_   67
#define M_   (B_*S_)     // 137216
#define HID_ 512
#define H_   8
#define KVH_ 4
#define D_   64

__device__ __forceinline__ unsigned f2bf_u(float f){
  union { __hip_bfloat16 h; unsigned short u; } c; c.h = __float2bfloat16(f); return (unsigned)c.u;
}
__device__ __forceinline__ float bfu2f(unsigned u){
  union { unsigned short u; __hip_bfloat16 h; } c; c.u = (unsigned short)u; return __bfloat162float(c.h);
}
__device__ __forceinline__ unsigned pack2(float a, float b){ return f2bf_u(a) | (f2bf_u(b) << 16); }

__device__ __forceinline__ void unpack8(uint4 v, float* o){
  o[0]=bfu2f(v.x & 0xffffu); o[1]=bfu2f(v.x >> 16);
  o[2]=bfu2f(v.y & 0xffffu); o[3]=bfu2f(v.y >> 16);
  o[4]=bfu2f(v.z & 0xffffu); o[5]=bfu2f(v.z >> 16);
  o[6]=bfu2f(v.w & 0xffffu); o[7]=bfu2f(v.w >> 16);
}

union S8 { short8 v; unsigned short u[8]; };

// ---------------- x fp32 -> bf16 convert ----------------
__global__ __launch_bounds__(256) void cvt_bf16(const float* __restrict__ src,
                                                unsigned short* __restrict__ dst){
  long i = (long)blockIdx.x*256 + threadIdx.x;   // one uint4 (8 bf16) per thread
  const float4 a = reinterpret_cast<const float4*>(src)[2*i];
  const float4 b = reinterpret_cast<const float4*>(src)[2*i+1];
  uint4 u = { pack2(a.x,a.y), pack2(a.z,a.w), pack2(b.x,b.y), pack2(b.z,b.w) };
  reinterpret_cast<uint4*>(dst)[i] = u;
}

// ---------------- weight transpose + bf16 convert ----------------
__global__ __launch_bounds__(256) void transpose_w(const float* __restrict__ src, int ncols,
                                                   unsigned short* __restrict__ dst, int row0){
  __shared__ float tile[32][33];
  const int tx = threadIdx.x & 31, ty = threadIdx.x >> 5;
  const int nb = blockIdx.x * 32, kb = blockIdx.y * 32;
  #pragma unroll
  for (int i = 0; i < 4; ++i){
    int r = ty + i*8;
    tile[r][tx] = src[(size_t)(kb + r)*ncols + nb + tx];
  }
  __syncthreads();
  #pragma unroll
  for (int i = 0; i < 4; ++i){
    int r = ty + i*8; // n within tile
    dst[(size_t)(row0 + nb + r)*512 + kb + tx] = (unsigned short)f2bf_u(tile[tx][r]);
  }
}

// ---------------- bf16 MFMA GEMM, double-buffered 2-phase pipeline ----------------
// out[M][Nld] = A[M][512] @ Bw^T  (Bw is [Nld][512] bf16, k-contiguous)
// 128x128 tile, BK=64. global_load_lds w=16, pre-swizzled global source (linear LDS
// dest), XOR-swizzled ds_read_b128. Counted vmcnt(8): next tile's 8 loads stay in
// flight across the barrier (T3-minimum recipe).
template<bool OUT_F32>
__global__ __launch_bounds__(256, 2) void gemm2_k(const unsigned short* __restrict__ A,
                                                  const unsigned short* __restrict__ Bw,
                                                  void* __restrict__ outp, int nbx){
  __shared__ unsigned short Sh[2][2][128*64];   // [dbuf][A|B][128 rows x 64 k]

  const int Nld = nbx << 7;
  // bijective XCD swizzle (gridDim.x divisible by 8)
  const int per = gridDim.x >> 3;
  const int wg  = (blockIdx.x & 7) * per + (blockIdx.x >> 3);
  const int m0 = (wg / nbx) * 128;
  const int n0 = (wg % nbx) * 128;

  const int t = threadIdx.x;
  const int l = t & 63;
  const int w = t >> 6;
  const int wr = w >> 1, wc = w & 1;
  const int lr = l & 15, lk = l >> 4;

  // staging: lane i covers LDS slot [row8=i>>3][kblk_phys=i&7]; logical kblk = (i&7)^(i>>3)
  const int srow  = w*32 + (l >> 3);
  const int skblk = (l & 7) ^ (l >> 3);
  const unsigned short* Ag = A  + (size_t)(m0 + srow)*512 + skblk*8;
  const unsigned short* Bg = Bw + (size_t)(n0 + srow)*512 + skblk*8;

  f32x4 acc[4][4];
  #pragma unroll
  for (int f = 0; f < 4; ++f)
    #pragma unroll
    for (int g = 0; g < 4; ++g) acc[f][g] = (f32x4){0.f, 0.f, 0.f, 0.f};

#define STAGE_(tt) do{ \
    unsigned short* As_ = &Sh[(tt)&1][0][0]; \
    unsigned short* Bs_ = &Sh[(tt)&1][1][0]; \
    _Pragma("unroll") \
    for (int j = 0; j < 4; ++j){ \
      __builtin_amdgcn_global_load_lds((const unsigned int*)(Ag + (size_t)(j*8)*512 + (tt)*64), \
                                       (unsigned int*)(As_ + (w*32 + j*8)*64), 16, 0, 0); \
      __builtin_amdgcn_global_load_lds((const unsigned int*)(Bg + (size_t)(j*8)*512 + (tt)*64), \
                                       (unsigned int*)(Bs_ + (w*32 + j*8)*64), 16, 0, 0); \
    } }while(0)

  STAGE_(0);
  #pragma unroll
  for (int tt = 0; tt < 8; ++tt){
    if (tt < 7) STAGE_(tt + 1);                     // 8 loads for next tile, in flight
    if (tt < 7) asm volatile("s_waitcnt vmcnt(8)" ::: "memory");   // cur tile landed
    else        asm volatile("s_waitcnt vmcnt(0)" ::: "memory");
    __builtin_amdgcn_s_barrier();
    __builtin_amdgcn_sched_barrier(0);

    const unsigned short* As = &Sh[tt&1][0][0];
    const unsigned short* Bs = &Sh[tt&1][1][0];
    #pragma unroll
    for (int ks = 0; ks < 2; ++ks){
      const int pk = ((ks*4 + lk) ^ (l & 7)) * 8;   // row&7 == l&7 for all frag rows
      short8 av[4], bv[4];
      #pragma unroll
      for (int f = 0; f < 4; ++f){
        av[f] = *reinterpret_cast<const short8*>(As + (wr*64 + f*16 + lr)*64 + pk);
        bv[f] = *reinterpret_cast<const short8*>(Bs + (wc*64 + f*16 + lr)*64 + pk);
      }
      #pragma unroll
      for (int f = 0; f < 4; ++f)
        #pragma unroll
        for (int g = 0; g < 4; ++g)
          acc[f][g] = __builtin_amdgcn_mfma_f32_16x16x32_bf16(av[f], bv[g], acc[f][g], 0, 0, 0);
    }
    asm volatile("s_waitcnt lgkmcnt(0)" ::: "memory");  // my ds_reads done before peers restage
    __builtin_amdgcn_sched_barrier(0);
    __builtin_amdgcn_s_barrier();
  }
#undef STAGE_

  if (OUT_F32){
    float* out = (float*)outp;
    #pragma unroll
    for (int f = 0; f < 4; ++f)
      #pragma unroll
      for (int g = 0; g < 4; ++g)
        #pragma unroll
        for (int r = 0; r < 4; ++r){
          size_t row = (size_t)(m0 + wr*64 + f*16 + lk*4 + r);
          out[row*Nld + n0 + wc*64 + g*16 + lr] = acc[f][g][r];
        }
  } else {
    // C -> LDS (32 KB of Sh) -> fully coalesced uint4 stores
    __syncthreads();
    unsigned short* Cs = &Sh[0][0][0];
    #pragma unroll
    for (int f = 0; f < 4; ++f)
      #pragma unroll
      for (int g = 0; g < 4; ++g)
        #pragma unroll
        for (int r = 0; r < 4; ++r){
          int row = wr*64 + f*16 + lk*4 + r;
          int col = wc*64 + g*16 + lr;
          Cs[row*128 + col] = (unsigned short)f2bf_u(acc[f][g][r]);
        }
    __syncthreads();
    unsigned short* out = (unsigned short*)outp;
    const uint4* Cv = reinterpret_cast<const uint4*>(Cs);
    #pragma unroll
    for (int p = 0; p < 8; ++p){
      int idx = p*256 + t;              // 2048 uint4 = 128 rows x 256B
      int row = idx >> 4, c8 = idx & 15;
      *reinterpret_cast<uint4*>(out + (size_t)(m0 + row)*Nld + n0 + c8*8) = Cv[idx];
    }
  }
}

// ---------------- MFMA attention: one block per (b, kvh), 5 waves ----------------
// All global loads hoisted to kernel top (max memory-level parallelism);
// RMSNorm in registers (norm weights folded into K); softmax in registers;
// P via wave-private swizzled LDS; V^T in swizzled LDS (d>>3 folded into swizzle).
__global__ __launch_bounds__(320, 2) void attn_k(const unsigned short* __restrict__ qkv,
                                                 const float* __restrict__ qnw,
                                                 const float* __restrict__ knw,
                                                 unsigned short* __restrict__ attn){
  __shared__ unsigned short Vt[64*128];       // V^T [d][s pad 128], swizzled
  __shared__ unsigned short Pb[5][16*128];    // per-wave P [16 rows][s pad 128], swizzled
  const int t = threadIdx.x;
  const int b = blockIdx.x >> 2, kvh = blockIdx.x & 3;
  const size_t rowbase = (size_t)b * 67;
  const int l = t & 63, w = t >> 6;
  const int lr = l & 15, lk = l >> 4;

  // ---------- issue ALL global loads up front ----------
  const int vsr = t >> 2, vdq = (t & 3) << 4;
  uint4 va = {0u,0u,0u,0u}, vb = {0u,0u,0u,0u};
  if (vsr < 67){
    const unsigned short* vp = qkv + (rowbase + vsr)*1024 + 768 + kvh*64 + vdq;
    va = *reinterpret_cast<const uint4*>(vp);
    vb = *reinterpret_cast<const uint4*>(vp + 8);
  }
  uint4 ku0[5], ku1[5];
  #pragma unroll
  for (int nt = 0; nt < 5; ++nt){
    int s = nt*16 + lr; if (s > 66) s = 66;
    const unsigned short* kp = qkv + (rowbase + s)*1024 + 512 + kvh*64 + lk*8;
    ku0[nt] = *reinterpret_cast<const uint4*>(kp);
    ku1[nt] = *reinterpret_cast<const uint4*>(kp + 32);
  }
  uint4 qu0[2], qu1[2];
  #pragma unroll
  for (int pass = 0; pass < 2; ++pass){
    const int st = w + pass*5;
    const int h = kvh*2 + st/5;
    int qr = (st%5)*16 + lr; if (qr > 66) qr = 66;
    const unsigned short* qp = qkv + (rowbase + qr)*1024 + h*64 + lk*8;
    qu0[pass] = *reinterpret_cast<const uint4*>(qp);
    qu1[pass] = *reinterpret_cast<const uint4*>(qp + 32);
  }
  float wp[16];
  #pragma unroll
  for (int ks = 0; ks < 2; ++ks)
    #pragma unroll
    for (int j = 0; j < 8; ++j){
      int idx = ks*32 + lk*8 + j;
      wp[ks*8+j] = qnw[idx] * knw[idx];
    }

  // ---------- stage V^T (swizzle: blk = (s>>3) ^ ((d&7)<<1) ^ (d>>3)) ----------
  {
    unsigned short vs[16];
    vs[0]=va.x&0xffffu; vs[1]=va.x>>16; vs[2]=va.y&0xffffu; vs[3]=va.y>>16;
    vs[4]=va.z&0xffffu; vs[5]=va.z>>16; vs[6]=va.w&0xffffu; vs[7]=va.w>>16;
    vs[8]=vb.x&0xffffu; vs[9]=vb.x>>16; vs[10]=vb.y&0xffffu; vs[11]=vb.y>>16;
    vs[12]=vb.z&0xffffu; vs[13]=vb.z>>16; vs[14]=vb.w&0xffffu; vs[15]=vb.w>>16;
    #pragma unroll
    for (int j = 0; j < 16; ++j){
      int d = vdq + j;
      int blk = ((vsr>>3) ^ ((d&7)<<1) ^ (d>>3)) & 15;
      Vt[(d<<7) + (blk<<3) + (vsr&7)] = vs[j];   // vs==0 for vsr>=67
    }
    if (t < 64){                                  // zero pad rows s=80..95
      int sr2 = 80 + (t >> 2);
      #pragma unroll
      for (int j = 0; j < 16; ++j){
        int d = vdq + j;
        int blk = ((sr2>>3) ^ ((d&7)<<1) ^ (d>>3)) & 15;
        Vt[(d<<7) + (blk<<3) + (sr2&7)] = 0;
      }
    }
  }

  // ---------- K fragments, normed + q*k-weighted ----------
  short8 kf[5][2];
  #pragma unroll
  for (int nt = 0; nt < 5; ++nt){
    float f[16]; unpack8(ku0[nt], f); unpack8(ku1[nt], f + 8);
    float ss = 0.f;
    #pragma unroll
    for (int j = 0; j < 16; ++j) ss += f[j]*f[j];
    ss += __shfl_xor(ss, 16); ss += __shfl_xor(ss, 32);
    float inv = rsqrtf(ss*(1.0f/64.0f) + 1e-5f);
    S8 a0, a1;
    #pragma unroll
    for (int j = 0; j < 8; ++j){
      a0.u[j] = (unsigned short)f2bf_u(f[j]   * inv * wp[j]);
      a1.u[j] = (unsigned short)f2bf_u(f[8+j] * inv * wp[8+j]);
    }
    kf[nt][0] = a0.v; kf[nt][1] = a1.v;
  }

  // ---------- zero my wave's Pb ----------
  {
    uint4 z = {0u,0u,0u,0u};
    uint4* pz = reinterpret_cast<uint4*>(Pb[w]);
    for (int i = l; i < 256; i += 64) pz[i] = z;
  }
  __syncthreads();

  #pragma unroll
  for (int pass = 0; pass < 2; ++pass){
    const int st = w + pass*5;           // 0..9
    const int g = st / 5, ms = (st % 5) * 16;
    const int h = kvh*2 + g;

    // ---- Q fragments, normed (weights folded into K) ----
    short8 qf0, qf1;
    {
      float f[16]; unpack8(qu0[pass], f); unpack8(qu1[pass], f + 8);
      float ss = 0.f;
      #pragma unroll
      for (int j = 0; j < 16; ++j) ss += f[j]*f[j];
      ss += __shfl_xor(ss, 16); ss += __shfl_xor(ss, 32);
      float inv = rsqrtf(ss*(1.0f/64.0f) + 1e-5f);
      S8 a0, a1;
      #pragma unroll
      for (int j = 0; j < 8; ++j){
        a0.u[j] = (unsigned short)f2bf_u(f[j]   * inv);
        a1.u[j] = (unsigned short)f2bf_u(f[8+j] * inv);
      }
      qf0 = a0.v; qf1 = a1.v;
    }

    // ---- QK^T ----
    f32x4 sa[5];
    #pragma unroll
    for (int nt = 0; nt < 5; ++nt){
      sa[nt] = (f32x4){0.f,0.f,0.f,0.f};
      sa[nt] = __builtin_amdgcn_mfma_f32_16x16x32_bf16(qf0, kf[nt][0], sa[nt], 0,0,0);
      sa[nt] = __builtin_amdgcn_mfma_f32_16x16x32_bf16(qf1, kf[nt][1], sa[nt], 0,0,0);
    }

    // ---- in-register softmax (lane holds S[lk*4+r][nt*16+lr]) ----
    #pragma unroll
    for (int r = 0; r < 4; ++r){
      float mx = -1e30f;
      #pragma unroll
      for (int nt = 0; nt < 5; ++nt){
        float v = sa[nt][r]*0.125f;
        if (nt*16 + lr >= 67) v = -1e30f;
        sa[nt][r] = v; mx = fmaxf(mx, v);
      }
      mx = fmaxf(mx, __shfl_xor(mx, 1));
      mx = fmaxf(mx, __shfl_xor(mx, 2));
      mx = fmaxf(mx, __shfl_xor(mx, 4));
      mx = fmaxf(mx, __shfl_xor(mx, 8));
      float sm = 0.f;
      #pragma unroll
      for (int nt = 0; nt < 5; ++nt){
        float e = __expf(sa[nt][r] - mx);
        sa[nt][r] = e; sm += e;
      }
      sm += __shfl_xor(sm, 1);
      sm += __shfl_xor(sm, 2);
      sm += __shfl_xor(sm, 4);
      sm += __shfl_xor(sm, 8);
      float inv = 1.0f / sm;
      #pragma unroll
      for (int nt = 0; nt < 5; ++nt) sa[nt][r] *= inv;
    }

    // ---- P -> wave-private swizzled LDS (bf16) ----
    unsigned short* pb = Pb[w];
    #pragma unroll
    for (int nt = 0; nt < 5; ++nt)
      #pragma unroll
      for (int r = 0; r < 4; ++r){
        int row = lk*4 + r, col = nt*16 + lr;
        pb[(row<<7) + ((((col>>3) ^ ((row&7)<<1))) << 3) + (col&7)] =
            (unsigned short)f2bf_u(sa[nt][r]);
      }

    // ---- PV ----
    f32x4 oa[4];
    #pragma unroll
    for (int dt = 0; dt < 4; ++dt) oa[dt] = (f32x4){0.f,0.f,0.f,0.f};
    #pragma unroll
    for (int ks = 0; ks < 3; ++ks){
      int blkp = (lk + ks*4) ^ ((lr & 7) << 1);
      short8 pf = *reinterpret_cast<const short8*>(&pb[(lr<<7) + (blkp<<3)]);
      #pragma unroll
      for (int dt = 0; dt < 4; ++dt){
        int d = dt*16 + lr;
        int blkv = ((lk + ks*4) ^ ((d & 7) << 1) ^ (d >> 3)) & 15;
        short8 vf = *reinterpret_cast<const short8*>(&Vt[(d<<7) + (blkv<<3)]);
        oa[dt] = __builtin_amdgcn_mfma_f32_16x16x32_bf16(pf, vf, oa[dt], 0,0,0);
      }
    }

    // ---- write O ----
    #pragma unroll
    for (int dt = 0; dt < 4; ++dt)
      #pragma unroll
      for (int r = 0; r < 4; ++r){
        int row = ms + lk*4 + r;
        if (row < 67)
          attn[(rowbase + row)*512 + h*64 + dt*16 + lr] = (unsigned short)f2bf_u(oa[dt][r]);
      }
  }
}

extern "C" void kernel_launch(void* const* d_in, const int* in_sizes, int n_in,
                              void* d_out, int out_size, void* d_ws, size_t ws_size,
                              hipStream_t stream){
  const float* x   = (const float*)d_in[0];
  const float* wq  = (const float*)d_in[1];
  const float* wk  = (const float*)d_in[2];
  const float* wv  = (const float*)d_in[3];
  const float* wo  = (const float*)d_in[4];
  const float* qnw = (const float*)d_in[5];
  const float* knw = (const float*)d_in[6];

  unsigned short* Wt   = (unsigned short*)d_ws;          // [1024][512] bf16
  unsigned short* Wot  = Wt + 1024*512;                  // [512][512] bf16
  unsigned short* qkv  = Wot + 512*512;                  // [M][1024] bf16
  unsigned short* attn = qkv + (size_t)M_*1024;          // [M][512] bf16
  unsigned short* xb   = attn;                           // alias: xb dead before attn written

  // weight prep (tiny)
  transpose_w<<<dim3(16,16), 256, 0, stream>>>(wq, 512, Wt, 0);
  transpose_w<<<dim3(8,16),  256, 0, stream>>>(wk, 256, Wt, 512);
  transpose_w<<<dim3(8,16),  256, 0, stream>>>(wv, 256, Wt, 768);
  transpose_w<<<dim3(16,16), 256, 0, stream>>>(wo, 512, Wot, 0);

  // x -> bf16
  cvt_bf16<<<(M_*512/8 + 255)/256, 256, 0, stream>>>(x, xb);

  // QKV projection: [M][512] bf16 @ -> [M][1024] bf16
  gemm2_k<false><<<dim3(8 * (M_/128)), 256, 0, stream>>>(xb, Wt, qkv, 8);

  // attention (MFMA, RMSNorm fused in registers)
  attn_k<<<dim3(B_*KVH_), 320, 0, stream>>>(qkv, qnw, knw, attn);

  // output projection: [M][512] bf16 @ -> [M][512] fp32
  gemm2_k<true><<<dim3(4 * (M_/128)), 256, 0, stream>>>(attn, Wot, d_out, 4);
}

// Round 5
// 609.405 us; speedup vs baseline: 2.2160x; 1.1568x over previous
//
#include <hip/hip_runtime.h>
#include <hip/hip_bf16.h>

typedef __attribute__((ext_vector_type(8))) short short8;
typedef __attribute__((ext_vector_type(4))) float f32x4;

#define B_   2048
#define S_   67
#define M_   (B_*S_)     // 137216
#define HID_ 512
#define H_   8
#define KVH_ 4
#define D_   64

__device__ __forceinline__ unsigned f2bf_u(float f){
  union { __hip_bfloat16 h; unsigned short u; } c; c.h = __float2bfloat16(f); return (unsigned)c.u;
}
__device__ __forceinline__ float bfu2f(unsigned u){
  union { unsigned short u; __hip_bfloat16 h; } c; c.u = (unsigned short)u; return __bfloat162float(c.h);
}
__device__ __forceinline__ unsigned pack2(float a, float b){ return f2bf_u(a) | (f2bf_u(b) << 16); }

__device__ __forceinline__ void unpack8(uint4 v, float* o){
  o[0]=bfu2f(v.x & 0xffffu); o[1]=bfu2f(v.x >> 16);
  o[2]=bfu2f(v.y & 0xffffu); o[3]=bfu2f(v.y >> 16);
  o[4]=bfu2f(v.z & 0xffffu); o[5]=bfu2f(v.z >> 16);
  o[6]=bfu2f(v.w & 0xffffu); o[7]=bfu2f(v.w >> 16);
}

union S8 { short8 v; unsigned short u[8]; };

// ---------------- x fp32 -> bf16 convert ----------------
__global__ __launch_bounds__(256) void cvt_bf16(const float* __restrict__ src,
                                                unsigned short* __restrict__ dst){
  long i = (long)blockIdx.x*256 + threadIdx.x;   // one uint4 (8 bf16) per thread
  const float4 a = reinterpret_cast<const float4*>(src)[2*i];
  const float4 b = reinterpret_cast<const float4*>(src)[2*i+1];
  uint4 u = { pack2(a.x,a.y), pack2(a.z,a.w), pack2(b.x,b.y), pack2(b.z,b.w) };
  reinterpret_cast<uint4*>(dst)[i] = u;
}

// ---------------- weight transpose + bf16 convert ----------------
__global__ __launch_bounds__(256) void transpose_w(const float* __restrict__ src, int ncols,
                                                   unsigned short* __restrict__ dst, int row0){
  __shared__ float tile[32][33];
  const int tx = threadIdx.x & 31, ty = threadIdx.x >> 5;
  const int nb = blockIdx.x * 32, kb = blockIdx.y * 32;
  #pragma unroll
  for (int i = 0; i < 4; ++i){
    int r = ty + i*8;
    tile[r][tx] = src[(size_t)(kb + r)*ncols + nb + tx];
  }
  __syncthreads();
  #pragma unroll
  for (int i = 0; i < 4; ++i){
    int r = ty + i*8; // n within tile
    dst[(size_t)(row0 + nb + r)*512 + kb + tx] = (unsigned short)f2bf_u(tile[tx][r]);
  }
}

// ---------------- bf16 MFMA GEMM, double-buffered 2-phase pipeline ----------------
template<bool OUT_F32>
__global__ __launch_bounds__(256, 2) void gemm2_k(const unsigned short* __restrict__ A,
                                                  const unsigned short* __restrict__ Bw,
                                                  void* __restrict__ outp, int nbx){
  __shared__ unsigned short Sh[2][2][128*64];   // [dbuf][A|B][128 rows x 64 k]

  const int Nld = nbx << 7;
  const int per = gridDim.x >> 3;
  const int wg  = (blockIdx.x & 7) * per + (blockIdx.x >> 3);
  const int m0 = (wg / nbx) * 128;
  const int n0 = (wg % nbx) * 128;

  const int t = threadIdx.x;
  const int l = t & 63;
  const int w = t >> 6;
  const int wr = w >> 1, wc = w & 1;
  const int lr = l & 15, lk = l >> 4;

  const int srow  = w*32 + (l >> 3);
  const int skblk = (l & 7) ^ (l >> 3);
  const unsigned short* Ag = A  + (size_t)(m0 + srow)*512 + skblk*8;
  const unsigned short* Bg = Bw + (size_t)(n0 + srow)*512 + skblk*8;

  f32x4 acc[4][4];
  #pragma unroll
  for (int f = 0; f < 4; ++f)
    #pragma unroll
    for (int g = 0; g < 4; ++g) acc[f][g] = (f32x4){0.f, 0.f, 0.f, 0.f};

#define STAGE_(tt) do{ \
    unsigned short* As_ = &Sh[(tt)&1][0][0]; \
    unsigned short* Bs_ = &Sh[(tt)&1][1][0]; \
    _Pragma("unroll") \
    for (int j = 0; j < 4; ++j){ \
      __builtin_amdgcn_global_load_lds((const unsigned int*)(Ag + (size_t)(j*8)*512 + (tt)*64), \
                                       (unsigned int*)(As_ + (w*32 + j*8)*64), 16, 0, 0); \
      __builtin_amdgcn_global_load_lds((const unsigned int*)(Bg + (size_t)(j*8)*512 + (tt)*64), \
                                       (unsigned int*)(Bs_ + (w*32 + j*8)*64), 16, 0, 0); \
    } }while(0)

  STAGE_(0);
  #pragma unroll
  for (int tt = 0; tt < 8; ++tt){
    if (tt < 7) STAGE_(tt + 1);
    if (tt < 7) asm volatile("s_waitcnt vmcnt(8)" ::: "memory");
    else        asm volatile("s_waitcnt vmcnt(0)" ::: "memory");
    __builtin_amdgcn_s_barrier();
    __builtin_amdgcn_sched_barrier(0);

    const unsigned short* As = &Sh[tt&1][0][0];
    const unsigned short* Bs = &Sh[tt&1][1][0];
    #pragma unroll
    for (int ks = 0; ks < 2; ++ks){
      const int pk = ((ks*4 + lk) ^ (l & 7)) * 8;
      short8 av[4], bv[4];
      #pragma unroll
      for (int f = 0; f < 4; ++f){
        av[f] = *reinterpret_cast<const short8*>(As + (wr*64 + f*16 + lr)*64 + pk);
        bv[f] = *reinterpret_cast<const short8*>(Bs + (wc*64 + f*16 + lr)*64 + pk);
      }
      #pragma unroll
      for (int f = 0; f < 4; ++f)
        #pragma unroll
        for (int g = 0; g < 4; ++g)
          acc[f][g] = __builtin_amdgcn_mfma_f32_16x16x32_bf16(av[f], bv[g], acc[f][g], 0, 0, 0);
    }
    asm volatile("s_waitcnt lgkmcnt(0)" ::: "memory");
    __builtin_amdgcn_sched_barrier(0);
    __builtin_amdgcn_s_barrier();
  }
#undef STAGE_

  if (OUT_F32){
    float* out = (float*)outp;
    #pragma unroll
    for (int f = 0; f < 4; ++f)
      #pragma unroll
      for (int g = 0; g < 4; ++g)
        #pragma unroll
        for (int r = 0; r < 4; ++r){
          size_t row = (size_t)(m0 + wr*64 + f*16 + lk*4 + r);
          out[row*Nld + n0 + wc*64 + g*16 + lr] = acc[f][g][r];
        }
  } else {
    __syncthreads();
    unsigned short* Cs = &Sh[0][0][0];
    #pragma unroll
    for (int f = 0; f < 4; ++f)
      #pragma unroll
      for (int g = 0; g < 4; ++g)
        #pragma unroll
        for (int r = 0; r < 4; ++r){
          int row = wr*64 + f*16 + lk*4 + r;
          int col = wc*64 + g*16 + lr;
          Cs[row*128 + col] = (unsigned short)f2bf_u(acc[f][g][r]);
        }
    __syncthreads();
    unsigned short* out = (unsigned short*)outp;
    const uint4* Cv = reinterpret_cast<const uint4*>(Cs);
    #pragma unroll
    for (int p = 0; p < 8; ++p){
      int idx = p*256 + t;
      int row = idx >> 4, c8 = idx & 15;
      *reinterpret_cast<uint4*>(out + (size_t)(m0 + row)*Nld + n0 + c8*8) = Cv[idx];
    }
  }
}

// ---------------- MFMA attention v3: one block per (b,kvh), 9 waves, 1 strip/wave ----
// Both heads' 134 q-rows packed into 9 strips of 16. K-norm computed ONCE (waves 0-4,
// one fragment each) and shared via LDS. Softmax scale folded into K weights; softmax
// divide deferred to O epilogue. V^T and P in XOR-swizzled LDS.
__global__ __launch_bounds__(576, 5) void attn_k(const unsigned short* __restrict__ qkv,
                                                 const float* __restrict__ qnw,
                                                 const float* __restrict__ knw,
                                                 unsigned short* __restrict__ attn){
  __shared__ unsigned short Vt[64*128];          // 16 KB  V^T [d][s pad 128], swizzled
  __shared__ unsigned short Kf[5][2][64*8];      // 10 KB  K fragments (MFMA reg layout)
  __shared__ unsigned short Pb[9][16*128];       // 36 KB  per-wave P, swizzled
  const int t = threadIdx.x;
  const int b = blockIdx.x >> 2, kvh = blockIdx.x & 3;
  const size_t rowbase = (size_t)b * 67;
  const int l = t & 63, w = t >> 6;
  const int lr = l & 15, lk = l >> 4;

  // ---------- issue global loads up front ----------
  // V: thread -> (s = t>>3 in 0..71, d0 = (t&7)*8)
  const int vs = t >> 3, vd0 = (t & 7) << 3;
  uint4 vu = {0u,0u,0u,0u};
  if (vs < 67)
    vu = *reinterpret_cast<const uint4*>(qkv + (rowbase + vs)*1024 + 768 + kvh*64 + vd0);
  // K: waves 0..4, fragment nt = w
  uint4 ku0 = {0u,0u,0u,0u}, ku1 = {0u,0u,0u,0u};
  if (w < 5){
    int s = w*16 + lr; if (s > 66) s = 66;
    const unsigned short* kp = qkv + (rowbase + s)*1024 + 512 + kvh*64 + lk*8;
    ku0 = *reinterpret_cast<const uint4*>(kp);
    ku1 = *reinterpret_cast<const uint4*>(kp + 32);
  }
  // Q: strip w covers packed q-rows w*16 .. w*16+15 (row<67 -> head0, 67..133 -> head1)
  const int qrow = w*16 + lr;
  const int h01 = (qrow >= 67) ? 1 : 0;
  int qr = qrow - (h01 ? 67 : 0); if (qr > 66) qr = 66;
  const unsigned short* qp = qkv + (rowbase + qr)*1024 + (kvh*2 + h01)*64 + lk*8;
  const uint4 qu0 = *reinterpret_cast<const uint4*>(qp);
  const uint4 qu1 = *reinterpret_cast<const uint4*>(qp + 32);
  // folded norm weights (q*k*scale) for K fragments
  float wp[16];
  #pragma unroll
  for (int hh = 0; hh < 2; ++hh)
    #pragma unroll
    for (int j = 0; j < 8; ++j){
      int idx = hh*32 + lk*8 + j;
      wp[hh*8+j] = qnw[idx] * knw[idx] * 0.125f;
    }

  // ---------- stage V^T (swizzle blk = (s>>3) ^ ((d&7)<<1) ^ (d>>3)) ----------
  {
    unsigned short vsv[8];
    vsv[0]=vu.x&0xffffu; vsv[1]=vu.x>>16; vsv[2]=vu.y&0xffffu; vsv[3]=vu.y>>16;
    vsv[4]=vu.z&0xffffu; vsv[5]=vu.z>>16; vsv[6]=vu.w&0xffffu; vsv[7]=vu.w>>16;
    #pragma unroll
    for (int j = 0; j < 8; ++j){
      int d = vd0 + j;
      int blk = ((vs>>3) ^ (j<<1) ^ (t&7)) & 15;
      Vt[(d<<7) + (blk<<3) + (vs&7)] = vsv[j];     // zeros for vs >= 67
    }
    if (t < 192){                                  // zero pad rows s = 72..95
      int s2 = 72 + (t >> 3);
      #pragma unroll
      for (int j = 0; j < 8; ++j){
        int d = vd0 + j;
        int blk = ((s2>>3) ^ (j<<1) ^ (t&7)) & 15;
        Vt[(d<<7) + (blk<<3) + (s2&7)] = 0;
      }
    }
  }

  // ---------- K fragment nt = w (waves 0-4): norm + weight, share via LDS ----------
  if (w < 5){
    float f[16]; unpack8(ku0, f); unpack8(ku1, f + 8);
    float ss = 0.f;
    #pragma unroll
    for (int j = 0; j < 16; ++j) ss += f[j]*f[j];
    ss += __shfl_xor(ss, 16); ss += __shfl_xor(ss, 32);
    float inv = rsqrtf(ss*(1.0f/64.0f) + 1e-5f);
    S8 a0, a1;
    #pragma unroll
    for (int j = 0; j < 8; ++j){
      a0.u[j] = (unsigned short)f2bf_u(f[j]   * inv * wp[j]);
      a1.u[j] = (unsigned short)f2bf_u(f[8+j] * inv * wp[8+j]);
    }
    *reinterpret_cast<short8*>(&Kf[w][0][l*8]) = a0.v;
    *reinterpret_cast<short8*>(&Kf[w][1][l*8]) = a1.v;
  }

  // ---------- Q fragments, normed (weights folded into K) ----------
  short8 qf0, qf1;
  {
    float f[16]; unpack8(qu0, f); unpack8(qu1, f + 8);
    float ss = 0.f;
    #pragma unroll
    for (int j = 0; j < 16; ++j) ss += f[j]*f[j];
    ss += __shfl_xor(ss, 16); ss += __shfl_xor(ss, 32);
    float inv = rsqrtf(ss*(1.0f/64.0f) + 1e-5f);
    S8 a0, a1;
    #pragma unroll
    for (int j = 0; j < 8; ++j){
      a0.u[j] = (unsigned short)f2bf_u(f[j]   * inv);
      a1.u[j] = (unsigned short)f2bf_u(f[8+j] * inv);
    }
    qf0 = a0.v; qf1 = a1.v;
  }

  // ---------- zero my wave's Pb ----------
  {
    uint4 z = {0u,0u,0u,0u};
    uint4* pz = reinterpret_cast<uint4*>(Pb[w]);
    #pragma unroll
    for (int i = 0; i < 4; ++i) pz[l + i*64] = z;
  }
  __syncthreads();

  // ---------- QK^T (K frags from LDS) ----------
  f32x4 sa[5];
  #pragma unroll
  for (int nt = 0; nt < 5; ++nt){
    short8 k0 = *reinterpret_cast<const short8*>(&Kf[nt][0][l*8]);
    short8 k1 = *reinterpret_cast<const short8*>(&Kf[nt][1][l*8]);
    sa[nt] = (f32x4){0.f,0.f,0.f,0.f};
    sa[nt] = __builtin_amdgcn_mfma_f32_16x16x32_bf16(qf0, k0, sa[nt], 0,0,0);
    sa[nt] = __builtin_amdgcn_mfma_f32_16x16x32_bf16(qf1, k1, sa[nt], 0,0,0);
  }

  // ---------- in-register softmax (scale pre-folded; divide deferred) ----------
  float inv4[4];
  #pragma unroll
  for (int r = 0; r < 4; ++r){
    float mx = -1e30f;
    #pragma unroll
    for (int nt = 0; nt < 5; ++nt){
      float v = sa[nt][r];
      if (nt*16 + lr >= 67) v = -1e30f;
      sa[nt][r] = v; mx = fmaxf(mx, v);
    }
    mx = fmaxf(mx, __shfl_xor(mx, 1));
    mx = fmaxf(mx, __shfl_xor(mx, 2));
    mx = fmaxf(mx, __shfl_xor(mx, 4));
    mx = fmaxf(mx, __shfl_xor(mx, 8));
    float sm = 0.f;
    #pragma unroll
    for (int nt = 0; nt < 5; ++nt){
      float e = __expf(sa[nt][r] - mx);
      sa[nt][r] = e; sm += e;
    }
    sm += __shfl_xor(sm, 1);
    sm += __shfl_xor(sm, 2);
    sm += __shfl_xor(sm, 4);
    sm += __shfl_xor(sm, 8);
    inv4[r] = 1.0f / sm;
  }

  // ---------- P (unnormalized e) -> swizzled LDS ----------
  unsigned short* pb = Pb[w];
  #pragma unroll
  for (int nt = 0; nt < 5; ++nt)
    #pragma unroll
    for (int r = 0; r < 4; ++r){
      int row = lk*4 + r, col = nt*16 + lr;
      int blk = ((col>>3) ^ ((row&7)<<1) ^ (row>>3)) & 15;
      pb[(row<<7) + (blk<<3) + (col&7)] = (unsigned short)f2bf_u(sa[nt][r]);
    }

  // ---------- PV ----------
  f32x4 oa[4];
  #pragma unroll
  for (int dt = 0; dt < 4; ++dt) oa[dt] = (f32x4){0.f,0.f,0.f,0.f};
  #pragma unroll
  for (int ks = 0; ks < 3; ++ks){
    int blkp = ((ks*4 + lk) ^ ((lr&7)<<1) ^ (lr>>3)) & 15;
    short8 pf = *reinterpret_cast<const short8*>(&pb[(lr<<7) + (blkp<<3)]);
    #pragma unroll
    for (int dt = 0; dt < 4; ++dt){
      int d = dt*16 + lr;
      int blkv = ((ks*4 + lk) ^ ((d&7)<<1) ^ (d>>3)) & 15;
      short8 vf = *reinterpret_cast<const short8*>(&Vt[(d<<7) + (blkv<<3)]);
      oa[dt] = __builtin_amdgcn_mfma_f32_16x16x32_bf16(pf, vf, oa[dt], 0,0,0);
    }
  }

  // ---------- O epilogue: apply 1/sum, write ----------
  #pragma unroll
  for (int dt = 0; dt < 4; ++dt)
    #pragma unroll
    for (int r = 0; r < 4; ++r){
      int row = w*16 + lk*4 + r;            // packed q-row
      if (row < 134){
        int hh = (row >= 67) ? 1 : 0;
        int orow = row - (hh ? 67 : 0);
        attn[(rowbase + orow)*512 + (kvh*2 + hh)*64 + dt*16 + lr] =
            (unsigned short)f2bf_u(oa[dt][r] * inv4[r]);
      }
    }
}

extern "C" void kernel_launch(void* const* d_in, const int* in_sizes, int n_in,
                              void* d_out, int out_size, void* d_ws, size_t ws_size,
                              hipStream_t stream){
  const float* x   = (const float*)d_in[0];
  const float* wq  = (const float*)d_in[1];
  const float* wk  = (const float*)d_in[2];
  const float* wv  = (const float*)d_in[3];
  const float* wo  = (const float*)d_in[4];
  const float* qnw = (const float*)d_in[5];
  const float* knw = (const float*)d_in[6];

  unsigned short* Wt   = (unsigned short*)d_ws;          // [1024][512] bf16
  unsigned short* Wot  = Wt + 1024*512;                  // [512][512] bf16
  unsigned short* qkv  = Wot + 512*512;                  // [M][1024] bf16
  unsigned short* attn = qkv + (size_t)M_*1024;          // [M][512] bf16
  unsigned short* xb   = attn;                           // alias: xb dead before attn written

  // weight prep (tiny)
  transpose_w<<<dim3(16,16), 256, 0, stream>>>(wq, 512, Wt, 0);
  transpose_w<<<dim3(8,16),  256, 0, stream>>>(wk, 256, Wt, 512);
  transpose_w<<<dim3(8,16),  256, 0, stream>>>(wv, 256, Wt, 768);
  transpose_w<<<dim3(16,16), 256, 0, stream>>>(wo, 512, Wot, 0);

  // x -> bf16
  cvt_bf16<<<(M_*512/8 + 255)/256, 256, 0, stream>>>(x, xb);

  // QKV projection: [M][512] bf16 @ -> [M][1024] bf16
  gemm2_k<false><<<dim3(8 * (M_/128)), 256, 0, stream>>>(xb, Wt, qkv, 8);

  // attention (MFMA, single-pass, K-norm dedup)
  attn_k<<<dim3(B_*KVH_), 576, 0, stream>>>(qkv, qnw, knw, attn);

  // output projection: [M][512] bf16 @ -> [M][512] fp32
  gemm2_k<true><<<dim3(4 * (M_/128)), 256, 0, stream>>>(attn, Wot, d_out, 4);
}

// Round 6
// 598.917 us; speedup vs baseline: 2.2548x; 1.0175x over previous
//
#include <hip/hip_runtime.h>
#include <hip/hip_bf16.h>

typedef __attribute__((ext_vector_type(8))) short short8;
typedef __attribute__((ext_vector_type(4))) float f32x4;

#define B_   2048
#define S_   67
#define M_   (B_*S_)     // 137216
#define HID_ 512
#define H_   8
#define KVH_ 4
#define D_   64

__device__ __forceinline__ unsigned f2bf_u(float f){
  union { __hip_bfloat16 h; unsigned short u; } c; c.h = __float2bfloat16(f); return (unsigned)c.u;
}
__device__ __forceinline__ float bfu2f(unsigned u){
  union { unsigned short u; __hip_bfloat16 h; } c; c.u = (unsigned short)u; return __bfloat162float(c.h);
}
__device__ __forceinline__ unsigned pack2(float a, float b){ return f2bf_u(a) | (f2bf_u(b) << 16); }

__device__ __forceinline__ void unpack8(uint4 v, float* o){
  o[0]=bfu2f(v.x & 0xffffu); o[1]=bfu2f(v.x >> 16);
  o[2]=bfu2f(v.y & 0xffffu); o[3]=bfu2f(v.y >> 16);
  o[4]=bfu2f(v.z & 0xffffu); o[5]=bfu2f(v.z >> 16);
  o[6]=bfu2f(v.w & 0xffffu); o[7]=bfu2f(v.w >> 16);
}

union S8 { short8 v; unsigned short u[8]; };

// ---------------- x fp32 -> bf16 convert ----------------
__global__ __launch_bounds__(256) void cvt_bf16(const float* __restrict__ src,
                                                unsigned short* __restrict__ dst){
  long i = (long)blockIdx.x*256 + threadIdx.x;   // one uint4 (8 bf16) per thread
  const float4 a = reinterpret_cast<const float4*>(src)[2*i];
  const float4 b = reinterpret_cast<const float4*>(src)[2*i+1];
  uint4 u = { pack2(a.x,a.y), pack2(a.z,a.w), pack2(b.x,b.y), pack2(b.z,b.w) };
  reinterpret_cast<uint4*>(dst)[i] = u;
}

// ---------------- weight transpose + bf16 convert ----------------
__global__ __launch_bounds__(256) void transpose_w(const float* __restrict__ src, int ncols,
                                                   unsigned short* __restrict__ dst, int row0){
  __shared__ float tile[32][33];
  const int tx = threadIdx.x & 31, ty = threadIdx.x >> 5;
  const int nb = blockIdx.x * 32, kb = blockIdx.y * 32;
  #pragma unroll
  for (int i = 0; i < 4; ++i){
    int r = ty + i*8;
    tile[r][tx] = src[(size_t)(kb + r)*ncols + nb + tx];
  }
  __syncthreads();
  #pragma unroll
  for (int i = 0; i < 4; ++i){
    int r = ty + i*8; // n within tile
    dst[(size_t)(row0 + nb + r)*512 + kb + tx] = (unsigned short)f2bf_u(tile[tx][r]);
  }
}

// ---------------- bf16 MFMA GEMM: 256x256 tile, 8 waves, per-wave 128x64 ----------------
// out[M][Nld] = A[M][512] @ Bw^T  (Bw is [Nld][512] bf16, k-contiguous)
// BK=64, double-buffered LDS (128 KB), global_load_lds w=16 with pre-swizzled global
// source (linear LDS dest), XOR-swizzled ds_read_b128, counted vmcnt(8) pipeline,
// bijective XCD block swizzle. Per-wave 128x64 raises LDS intensity 32 -> 42.7 FLOP/B.
template<bool OUT_F32>
__global__ __launch_bounds__(512, 2) void gemm3_k(const unsigned short* __restrict__ A,
                                                  const unsigned short* __restrict__ Bw,
                                                  void* __restrict__ outp, int nbx){
  __shared__ unsigned short Sh[2][2][256*64];   // [dbuf][A|B][256 rows x 64 k] = 128 KB

  const int Nld = nbx << 8;
  const int per = gridDim.x >> 3;
  const int wg  = (blockIdx.x & 7) * per + (blockIdx.x >> 3);
  const int m0 = (wg / nbx) * 256;
  const int n0 = (wg % nbx) * 256;

  const int t = threadIdx.x;
  const int l = t & 63;
  const int w = t >> 6;                 // 0..7
  const int wr = w >> 2, wc = w & 3;    // wave tile: rows wr*128, cols wc*64
  const int lr = l & 15, lk = l >> 4;

  // staging: lane i covers LDS slot [row8=i>>3][kblk_phys=i&7]; logical kblk = (i&7)^(i>>3)
  const int srow  = w*32 + (l >> 3);
  const int skblk = (l & 7) ^ (l >> 3);
  const unsigned short* Ag = A  + (size_t)(m0 + srow)*512 + skblk*8;
  const unsigned short* Bg = Bw + (size_t)(n0 + srow)*512 + skblk*8;

  f32x4 acc[8][4];
  #pragma unroll
  for (int f = 0; f < 8; ++f)
    #pragma unroll
    for (int g = 0; g < 4; ++g) acc[f][g] = (f32x4){0.f, 0.f, 0.f, 0.f};

#define STAGE_(tt) do{ \
    unsigned short* As_ = &Sh[(tt)&1][0][0]; \
    unsigned short* Bs_ = &Sh[(tt)&1][1][0]; \
    _Pragma("unroll") \
    for (int j = 0; j < 4; ++j){ \
      __builtin_amdgcn_global_load_lds((const unsigned int*)(Ag + (size_t)(j*8)*512 + (tt)*64), \
                                       (unsigned int*)(As_ + (w*32 + j*8)*64), 16, 0, 0); \
      __builtin_amdgcn_global_load_lds((const unsigned int*)(Bg + (size_t)(j*8)*512 + (tt)*64), \
                                       (unsigned int*)(Bs_ + (w*32 + j*8)*64), 16, 0, 0); \
    } }while(0)

  STAGE_(0);
  #pragma unroll
  for (int tt = 0; tt < 8; ++tt){
    if (tt < 7) STAGE_(tt + 1);                     // next tile's 8 loads stay in flight
    if (tt < 7) asm volatile("s_waitcnt vmcnt(8)" ::: "memory");
    else        asm volatile("s_waitcnt vmcnt(0)" ::: "memory");
    __builtin_amdgcn_s_barrier();
    __builtin_amdgcn_sched_barrier(0);

    const unsigned short* As = &Sh[tt&1][0][0];
    const unsigned short* Bs = &Sh[tt&1][1][0];
    #pragma unroll
    for (int ks = 0; ks < 2; ++ks){
      const int pk = ((ks*4 + lk) ^ (l & 7)) * 8;   // row&7 == l&7 for all frag rows
      short8 av[8], bv[4];
      #pragma unroll
      for (int f = 0; f < 8; ++f)
        av[f] = *reinterpret_cast<const short8*>(As + (wr*128 + f*16 + lr)*64 + pk);
      #pragma unroll
      for (int g = 0; g < 4; ++g)
        bv[g] = *reinterpret_cast<const short8*>(Bs + (wc*64 + g*16 + lr)*64 + pk);
      #pragma unroll
      for (int f = 0; f < 8; ++f)
        #pragma unroll
        for (int g = 0; g < 4; ++g)
          acc[f][g] = __builtin_amdgcn_mfma_f32_16x16x32_bf16(av[f], bv[g], acc[f][g], 0, 0, 0);
    }
    asm volatile("s_waitcnt lgkmcnt(0)" ::: "memory");
    __builtin_amdgcn_sched_barrier(0);
    __builtin_amdgcn_s_barrier();
  }
#undef STAGE_

  if (OUT_F32){
    float* out = (float*)outp;
    #pragma unroll
    for (int f = 0; f < 8; ++f)
      #pragma unroll
      for (int g = 0; g < 4; ++g)
        #pragma unroll
        for (int r = 0; r < 4; ++r){
          size_t row = (size_t)(m0 + wr*128 + f*16 + lk*4 + r);
          out[row*Nld + n0 + wc*64 + g*16 + lr] = acc[f][g][r];
        }
  } else {
    // bf16 out via LDS half-tiles (128x256 = 64 KB), fully coalesced uint4 stores
    unsigned short* Cs = &Sh[0][0][0];
    unsigned short* out = (unsigned short*)outp;
    #pragma unroll
    for (int half = 0; half < 2; ++half){
      __syncthreads();
      if (wr == half){
        #pragma unroll
        for (int f = 0; f < 8; ++f)
          #pragma unroll
          for (int g = 0; g < 4; ++g)
            #pragma unroll
            for (int r = 0; r < 4; ++r){
              int row = f*16 + lk*4 + r;                 // 0..127 local
              int col = wc*64 + g*16 + lr;
              Cs[row*256 + col] = (unsigned short)f2bf_u(acc[f][g][r]);
            }
      }
      __syncthreads();
      const uint4* Cv = reinterpret_cast<const uint4*>(Cs);
      #pragma unroll
      for (int p = 0; p < 8; ++p){
        int idx = p*512 + t;            // 4096 uint4 = 128 rows x 32 u4
        int row = idx >> 5, c16 = idx & 31;
        *reinterpret_cast<uint4*>(out + (size_t)(m0 + half*128 + row)*Nld + n0 + c16*8) = Cv[idx];
      }
    }
  }
}

// ---------------- MFMA attention v3: one block per (b,kvh), 9 waves, 1 strip/wave ----
__global__ __launch_bounds__(576, 5) void attn_k(const unsigned short* __restrict__ qkv,
                                                 const float* __restrict__ qnw,
                                                 const float* __restrict__ knw,
                                                 unsigned short* __restrict__ attn){
  __shared__ unsigned short Vt[64*128];          // 16 KB  V^T [d][s pad 128], swizzled
  __shared__ unsigned short Kf[5][2][64*8];      // 10 KB  K fragments (MFMA reg layout)
  __shared__ unsigned short Pb[9][16*128];       // 36 KB  per-wave P, swizzled
  const int t = threadIdx.x;
  const int b = blockIdx.x >> 2, kvh = blockIdx.x & 3;
  const size_t rowbase = (size_t)b * 67;
  const int l = t & 63, w = t >> 6;
  const int lr = l & 15, lk = l >> 4;

  // ---------- issue global loads up front ----------
  const int vs = t >> 3, vd0 = (t & 7) << 3;
  uint4 vu = {0u,0u,0u,0u};
  if (vs < 67)
    vu = *reinterpret_cast<const uint4*>(qkv + (rowbase + vs)*1024 + 768 + kvh*64 + vd0);
  uint4 ku0 = {0u,0u,0u,0u}, ku1 = {0u,0u,0u,0u};
  if (w < 5){
    int s = w*16 + lr; if (s > 66) s = 66;
    const unsigned short* kp = qkv + (rowbase + s)*1024 + 512 + kvh*64 + lk*8;
    ku0 = *reinterpret_cast<const uint4*>(kp);
    ku1 = *reinterpret_cast<const uint4*>(kp + 32);
  }
  const int qrow = w*16 + lr;
  const int h01 = (qrow >= 67) ? 1 : 0;
  int qr = qrow - (h01 ? 67 : 0); if (qr > 66) qr = 66;
  const unsigned short* qp = qkv + (rowbase + qr)*1024 + (kvh*2 + h01)*64 + lk*8;
  const uint4 qu0 = *reinterpret_cast<const uint4*>(qp);
  const uint4 qu1 = *reinterpret_cast<const uint4*>(qp + 32);
  float wp[16];
  #pragma unroll
  for (int hh = 0; hh < 2; ++hh)
    #pragma unroll
    for (int j = 0; j < 8; ++j){
      int idx = hh*32 + lk*8 + j;
      wp[hh*8+j] = qnw[idx] * knw[idx] * 0.125f;
    }

  // ---------- stage V^T ----------
  {
    unsigned short vsv[8];
    vsv[0]=vu.x&0xffffu; vsv[1]=vu.x>>16; vsv[2]=vu.y&0xffffu; vsv[3]=vu.y>>16;
    vsv[4]=vu.z&0xffffu; vsv[5]=vu.z>>16; vsv[6]=vu.w&0xffffu; vsv[7]=vu.w>>16;
    #pragma unroll
    for (int j = 0; j < 8; ++j){
      int d = vd0 + j;
      int blk = ((vs>>3) ^ (j<<1) ^ (t&7)) & 15;
      Vt[(d<<7) + (blk<<3) + (vs&7)] = vsv[j];
    }
    if (t < 192){
      int s2 = 72 + (t >> 3);
      #pragma unroll
      for (int j = 0; j < 8; ++j){
        int d = vd0 + j;
        int blk = ((s2>>3) ^ (j<<1) ^ (t&7)) & 15;
        Vt[(d<<7) + (blk<<3) + (s2&7)] = 0;
      }
    }
  }

  // ---------- K fragment nt = w (waves 0-4): norm + weight, share via LDS ----------
  if (w < 5){
    float f[16]; unpack8(ku0, f); unpack8(ku1, f + 8);
    float ss = 0.f;
    #pragma unroll
    for (int j = 0; j < 16; ++j) ss += f[j]*f[j];
    ss += __shfl_xor(ss, 16); ss += __shfl_xor(ss, 32);
    float inv = rsqrtf(ss*(1.0f/64.0f) + 1e-5f);
    S8 a0, a1;
    #pragma unroll
    for (int j = 0; j < 8; ++j){
      a0.u[j] = (unsigned short)f2bf_u(f[j]   * inv * wp[j]);
      a1.u[j] = (unsigned short)f2bf_u(f[8+j] * inv * wp[8+j]);
    }
    *reinterpret_cast<short8*>(&Kf[w][0][l*8]) = a0.v;
    *reinterpret_cast<short8*>(&Kf[w][1][l*8]) = a1.v;
  }

  // ---------- Q fragments, normed ----------
  short8 qf0, qf1;
  {
    float f[16]; unpack8(qu0, f); unpack8(qu1, f + 8);
    float ss = 0.f;
    #pragma unroll
    for (int j = 0; j < 16; ++j) ss += f[j]*f[j];
    ss += __shfl_xor(ss, 16); ss += __shfl_xor(ss, 32);
    float inv = rsqrtf(ss*(1.0f/64.0f) + 1e-5f);
    S8 a0, a1;
    #pragma unroll
    for (int j = 0; j < 8; ++j){
      a0.u[j] = (unsigned short)f2bf_u(f[j]   * inv);
      a1.u[j] = (unsigned short)f2bf_u(f[8+j] * inv);
    }
    qf0 = a0.v; qf1 = a1.v;
  }

  // ---------- zero my wave's Pb ----------
  {
    uint4 z = {0u,0u,0u,0u};
    uint4* pz = reinterpret_cast<uint4*>(Pb[w]);
    #pragma unroll
    for (int i = 0; i < 4; ++i) pz[l + i*64] = z;
  }
  __syncthreads();

  // ---------- QK^T ----------
  f32x4 sa[5];
  #pragma unroll
  for (int nt = 0; nt < 5; ++nt){
    short8 k0 = *reinterpret_cast<const short8*>(&Kf[nt][0][l*8]);
    short8 k1 = *reinterpret_cast<const short8*>(&Kf[nt][1][l*8]);
    sa[nt] = (f32x4){0.f,0.f,0.f,0.f};
    sa[nt] = __builtin_amdgcn_mfma_f32_16x16x32_bf16(qf0, k0, sa[nt], 0,0,0);
    sa[nt] = __builtin_amdgcn_mfma_f32_16x16x32_bf16(qf1, k1, sa[nt], 0,0,0);
  }

  // ---------- in-register softmax (divide deferred) ----------
  float inv4[4];
  #pragma unroll
  for (int r = 0; r < 4; ++r){
    float mx = -1e30f;
    #pragma unroll
    for (int nt = 0; nt < 5; ++nt){
      float v = sa[nt][r];
      if (nt*16 + lr >= 67) v = -1e30f;
      sa[nt][r] = v; mx = fmaxf(mx, v);
    }
    mx = fmaxf(mx, __shfl_xor(mx, 1));
    mx = fmaxf(mx, __shfl_xor(mx, 2));
    mx = fmaxf(mx, __shfl_xor(mx, 4));
    mx = fmaxf(mx, __shfl_xor(mx, 8));
    float sm = 0.f;
    #pragma unroll
    for (int nt = 0; nt < 5; ++nt){
      float e = __expf(sa[nt][r] - mx);
      sa[nt][r] = e; sm += e;
    }
    sm += __shfl_xor(sm, 1);
    sm += __shfl_xor(sm, 2);
    sm += __shfl_xor(sm, 4);
    sm += __shfl_xor(sm, 8);
    inv4[r] = 1.0f / sm;
  }

  // ---------- P (unnormalized e) -> swizzled LDS ----------
  unsigned short* pb = Pb[w];
  #pragma unroll
  for (int nt = 0; nt < 5; ++nt)
    #pragma unroll
    for (int r = 0; r < 4; ++r){
      int row = lk*4 + r, col = nt*16 + lr;
      int blk = ((col>>3) ^ ((row&7)<<1) ^ (row>>3)) & 15;
      pb[(row<<7) + (blk<<3) + (col&7)] = (unsigned short)f2bf_u(sa[nt][r]);
    }

  // ---------- PV ----------
  f32x4 oa[4];
  #pragma unroll
  for (int dt = 0; dt < 4; ++dt) oa[dt] = (f32x4){0.f,0.f,0.f,0.f};
  #pragma unroll
  for (int ks = 0; ks < 3; ++ks){
    int blkp = ((ks*4 + lk) ^ ((lr&7)<<1) ^ (lr>>3)) & 15;
    short8 pf = *reinterpret_cast<const short8*>(&pb[(lr<<7) + (blkp<<3)]);
    #pragma unroll
    for (int dt = 0; dt < 4; ++dt){
      int d = dt*16 + lr;
      int blkv = ((ks*4 + lk) ^ ((d&7)<<1) ^ (d>>3)) & 15;
      short8 vf = *reinterpret_cast<const short8*>(&Vt[(d<<7) + (blkv<<3)]);
      oa[dt] = __builtin_amdgcn_mfma_f32_16x16x32_bf16(pf, vf, oa[dt], 0,0,0);
    }
  }

  // ---------- O epilogue: apply 1/sum, write ----------
  #pragma unroll
  for (int dt = 0; dt < 4; ++dt)
    #pragma unroll
    for (int r = 0; r < 4; ++r){
      int row = w*16 + lk*4 + r;
      if (row < 134){
        int hh = (row >= 67) ? 1 : 0;
        int orow = row - (hh ? 67 : 0);
        attn[(rowbase + orow)*512 + (kvh*2 + hh)*64 + dt*16 + lr] =
            (unsigned short)f2bf_u(oa[dt][r] * inv4[r]);
      }
    }
}

extern "C" void kernel_launch(void* const* d_in, const int* in_sizes, int n_in,
                              void* d_out, int out_size, void* d_ws, size_t ws_size,
                              hipStream_t stream){
  const float* x   = (const float*)d_in[0];
  const float* wq  = (const float*)d_in[1];
  const float* wk  = (const float*)d_in[2];
  const float* wv  = (const float*)d_in[3];
  const float* wo  = (const float*)d_in[4];
  const float* qnw = (const float*)d_in[5];
  const float* knw = (const float*)d_in[6];

  unsigned short* Wt   = (unsigned short*)d_ws;          // [1024][512] bf16
  unsigned short* Wot  = Wt + 1024*512;                  // [512][512] bf16
  unsigned short* qkv  = Wot + 512*512;                  // [M][1024] bf16
  unsigned short* attn = qkv + (size_t)M_*1024;          // [M][512] bf16
  unsigned short* xb   = attn;                           // alias: xb dead before attn written

  // weight prep (tiny)
  transpose_w<<<dim3(16,16), 256, 0, stream>>>(wq, 512, Wt, 0);
  transpose_w<<<dim3(8,16),  256, 0, stream>>>(wk, 256, Wt, 512);
  transpose_w<<<dim3(8,16),  256, 0, stream>>>(wv, 256, Wt, 768);
  transpose_w<<<dim3(16,16), 256, 0, stream>>>(wo, 512, Wot, 0);

  // x -> bf16
  cvt_bf16<<<(M_*512/8 + 255)/256, 256, 0, stream>>>(x, xb);

  // QKV projection: [M][512] bf16 @ -> [M][1024] bf16  (256x256 tiles: 536*4 blocks)
  gemm3_k<false><<<dim3(4 * (M_/256)), 512, 0, stream>>>(xb, Wt, qkv, 4);

  // attention (MFMA, single-pass, K-norm dedup)
  attn_k<<<dim3(B_*KVH_), 576, 0, stream>>>(qkv, qnw, knw, attn);

  // output projection: [M][512] bf16 @ -> [M][512] fp32  (536*2 blocks)
  gemm3_k<true><<<dim3(2 * (M_/256)), 512, 0, stream>>>(attn, Wot, d_out, 2);
}